// Round 8
// baseline (277.468 us; speedup 1.0000x reference)
//
#include <hip/hip_runtime.h>
#include <math.h>

#define N_NODES 50000
#define N_EDGESI 800000
#define E_TOT   850000      // + self loops
#define HIDDEN  128
#define HEADS   8
#define HEAD_DIM 16
#define INPUT   300
#define BATCH   64
#define NPART   8
#define PSZ     6250        // N_NODES / NPART

typedef __bf16 bf16_t;
typedef bf16_t bf16x8 __attribute__((ext_vector_type(8)));
typedef float  f32x4  __attribute__((ext_vector_type(4)));

__device__ __forceinline__ float bflo(unsigned u){ return __uint_as_float(u << 16); }
__device__ __forceinline__ float bfhi(unsigned u){ return __uint_as_float(u & 0xffff0000u); }

// ===== pack B (fp32 -> fragment-ready bf16 hi/lo planes) + fused Wa =====
// layout: plane[(k/8)*NCOL*8 + col*8 + (k%8)]
template<int K_REAL, int K_PAD, int NCOL, bool ALPHA>
__global__ void pack_b_kernel(const float* __restrict__ B128, const float* __restrict__ as,
                              const float* __restrict__ ad, bf16_t* __restrict__ bHi,
                              bf16_t* __restrict__ bLo){
    int idx = blockIdx.x*256 + threadIdx.x;
    if (idx >= K_PAD*NCOL) return;
    int k = idx / NCOL, col = idx % NCOL;
    float v = 0.f;
    if (k < K_REAL){
        if (!ALPHA || col < 128){
            v = B128[k*128 + col];
        } else {
            int jj = col - 128;                       // 0..15
            const float* a = (jj < 8) ? (as + jj*16) : (ad + (jj-8)*16);
            const float* wrow = B128 + k*128 + (jj & 7)*16;
            float s = 0.f;
            #pragma unroll
            for (int d = 0; d < 16; d++) s += wrow[d]*a[d];
            v = s;
        }
    }
    bf16_t hi = (bf16_t)v;
    bf16_t lo = (bf16_t)(v - (float)hi);
    int o = ((k >> 3)*NCOL + col)*8 + (k & 7);
    bHi[o] = hi; bLo[o] = lo;
}

// ===== MFMA GEMM, fp32 accuracy via bf16 hi/lo split, depth-3 A prefetch =====
// one wave = 16 rows x NCOL cols.  A fp32 from global via register pipeline.
template<int K_REAL, int NT, bool BIAS_EPI, bool ALPHA>
__global__ __launch_bounds__(256)
void mfma_gemm4_kernel(const float* __restrict__ A, const bf16_t* __restrict__ bHi,
                       const bf16_t* __restrict__ bLo, const float* __restrict__ bias,
                       float* __restrict__ outF, bf16_t* __restrict__ outH,
                       float* __restrict__ asrc_out, float* __restrict__ adst_out, int M)
{
    constexpr int NCOL   = NT * 16;
    constexpr int KSTEPS = (K_REAL + 31) / 32;
    constexpr int PD     = (KSTEPS < 3) ? KSTEPS : 3;   // prefetch depth
    int tid = threadIdx.x, lane = tid & 63, w = tid >> 6;
    int l15 = lane & 15, lg = lane >> 4;
    int m0 = (blockIdx.x*4 + w) * 16;
    if (m0 >= M) return;
    const float* arow = A + (size_t)(m0 + l15)*K_REAL;

    // prologue: fill pipeline (K_REAL % 4 == 0, so float4 loads never straddle)
    float4 pva[PD], pvb[PD];
    #pragma unroll
    for (int i = 0; i < PD; i++){
        int k0 = i*32 + lg*8;
        pva[i] = (k0 + 3 < K_REAL) ? *(const float4*)&arow[k0]     : (float4){0.f,0.f,0.f,0.f};
        pvb[i] = (k0 + 7 < K_REAL) ? *(const float4*)&arow[k0 + 4] : (float4){0.f,0.f,0.f,0.f};
    }

    f32x4 acc[NT];
    #pragma unroll
    for (int c = 0; c < NT; c++) acc[c] = (f32x4){0.f,0.f,0.f,0.f};

    #pragma unroll
    for (int ks = 0; ks < KSTEPS; ks++){
        const int sl = ks % PD;
        float4 va = pva[sl], vb = pvb[sl];
        float f[8] = {va.x, va.y, va.z, va.w, vb.x, vb.y, vb.z, vb.w};
        bf16x8 ah, al;
        #pragma unroll
        for (int q = 0; q < 8; q++){
            bf16_t hi = (bf16_t)f[q];
            ah[q] = hi;
            al[q] = (bf16_t)(f[q] - (float)hi);
        }
        // refill slot for step ks+PD (starts HBM fetch ~3 steps early)
        if (ks + PD < KSTEPS){
            int k0 = (ks + PD)*32 + lg*8;
            pva[sl] = (k0 + 3 < K_REAL) ? *(const float4*)&arow[k0]     : (float4){0.f,0.f,0.f,0.f};
            pvb[sl] = (k0 + 7 < K_REAL) ? *(const float4*)&arow[k0 + 4] : (float4){0.f,0.f,0.f,0.f};
        }
        int g = ks*4 + lg;
        const bf16_t* bh_base = bHi + ((size_t)g*NCOL + l15)*8;
        const bf16_t* bl_base = bLo + ((size_t)g*NCOL + l15)*8;
        #pragma unroll
        for (int c = 0; c < NT; c++){
            bf16x8 bh = *(const bf16x8*)&bh_base[c*128];
            bf16x8 bl = *(const bf16x8*)&bl_base[c*128];
            acc[c] = __builtin_amdgcn_mfma_f32_16x16x32_bf16(ah, bh, acc[c], 0,0,0);
            acc[c] = __builtin_amdgcn_mfma_f32_16x16x32_bf16(ah, bl, acc[c], 0,0,0);
            acc[c] = __builtin_amdgcn_mfma_f32_16x16x32_bf16(al, bh, acc[c], 0,0,0);
        }
    }

    // ---- epilogue: D col = lane&15, row = (lane>>4)*4 + reg ----
    #pragma unroll
    for (int c = 0; c < 8; c++){
        int col = c*16 + l15;
        float bv = BIAS_EPI ? bias[col] : 0.f;
        #pragma unroll
        for (int r = 0; r < 4; r++){
            int m = m0 + lg*4 + r;
            if (m < M){
                if (!ALPHA) outF[(size_t)m*128 + col] = acc[c][r] + bv;
                else        outH[(size_t)m*128 + col] = (bf16_t)acc[c][r];
            }
        }
    }
    if (ALPHA){
        #pragma unroll
        for (int r = 0; r < 4; r++){
            int m = m0 + lg*4 + r;
            if (m < M){
                float v = acc[8][r];
                if (l15 < 8) asrc_out[m*8 + l15]       = v;
                else         adst_out[m*8 + (l15 - 8)] = v;
            }
        }
    }
}

// ============== CSR build, XCD-partitioned by dst range ==============
__global__ __launch_bounds__(256)
void deg_part_kernel(const int* __restrict__ ei, int* __restrict__ deg){
    int part = blockIdx.x & 7;
    int bwp  = blockIdx.x >> 3;
    int nbp  = gridDim.x >> 3;
    int lo = part*PSZ, hi = lo + PSZ;
    for (int e = bwp*256 + threadIdx.x; e < E_TOT; e += nbp*256){
        int d = (e < N_EDGESI) ? ei[N_EDGESI + e] : (e - N_EDGESI);
        if (d >= lo && d < hi) atomicAdd(&deg[d], 1);
    }
}

__global__ __launch_bounds__(256)
void scatter_part_kernel(const int* __restrict__ ei, int* __restrict__ cursor,
                         int* __restrict__ col_src){
    int part = blockIdx.x & 7;
    int bwp  = blockIdx.x >> 3;
    int nbp  = gridDim.x >> 3;
    int lo = part*PSZ, hi = lo + PSZ;
    for (int e = bwp*256 + threadIdx.x; e < E_TOT; e += nbp*256){
        int d = (e < N_EDGESI) ? ei[N_EDGESI + e] : (e - N_EDGESI);
        if (d >= lo && d < hi){
            int s = (e < N_EDGESI) ? ei[e] : d;
            int pos = atomicAdd(&cursor[d], 1);
            col_src[pos] = s;
        }
    }
}

__global__ void scan_block_kernel(const int* __restrict__ deg, int* __restrict__ scanout,
                                  int* __restrict__ blocksums){
    __shared__ int buf[1024];
    int gid = blockIdx.x*1024 + threadIdx.x;
    int v = (gid < N_NODES) ? deg[gid] : 0;
    buf[threadIdx.x] = v;
    __syncthreads();
    for (int off = 1; off < 1024; off <<= 1){
        int t = (threadIdx.x >= off) ? buf[threadIdx.x - off] : 0;
        __syncthreads();
        buf[threadIdx.x] += t;
        __syncthreads();
    }
    if (gid < N_NODES) scanout[gid] = buf[threadIdx.x] - v;   // exclusive
    if (threadIdx.x == 1023) blocksums[blockIdx.x] = buf[1023];
}

// wave-parallel exclusive scan of <=64 block sums
__global__ void scan_sums_kernel(int* __restrict__ blocksums, int nb){
    int t = threadIdx.x;   // 64
    int orig = (t < nb) ? blocksums[t] : 0;
    int v = orig;
    #pragma unroll
    for (int off = 1; off < 64; off <<= 1){
        int u = __shfl_up(v, off);
        if (t >= off) v += u;
    }
    if (t < nb) blocksums[t] = v - orig;   // exclusive
}

__global__ void scan_add_kernel(const int* __restrict__ scanout, const int* __restrict__ blocksums,
                                int* __restrict__ row_ptr, int* __restrict__ cursor){
    int i = blockIdx.x*256 + threadIdx.x;
    if (i < N_NODES){
        int v = scanout[i] + blocksums[i >> 10];
        row_ptr[i] = v;
        cursor[i]  = v;
    }
    if (i == 0) row_ptr[N_NODES] = E_TOT;
}

// ===== fused per-dst softmax + aggregate + bias + ELU: one wave per node =====
__global__ __launch_bounds__(256)
void gat_aggregate_kernel(const int* __restrict__ row_ptr, const int* __restrict__ col_src,
                          const unsigned short* __restrict__ H, const float* __restrict__ a_s,
                          const float* __restrict__ a_d, const float* __restrict__ bias,
                          float* __restrict__ xout){
    __shared__ float alds[4][8][65];
    int wave = threadIdx.x >> 6;
    int lane = threadIdx.x & 63;
    int d = blockIdx.x*4 + wave;
    if (d >= N_NODES) return;
    int start = row_ptr[d], end = row_ptr[d + 1];
    int deg = end - start;                 // >= 1 (self loop)
    int hme = lane >> 3, seg = lane & 7;

    float ad_[8];
    {
        float4 t0 = *(const float4*)&a_d[d*8];
        float4 t1 = *(const float4*)&a_d[d*8 + 4];
        ad_[0]=t0.x; ad_[1]=t0.y; ad_[2]=t0.z; ad_[3]=t0.w;
        ad_[4]=t1.x; ad_[5]=t1.y; ad_[6]=t1.z; ad_[7]=t1.w;
    }

    float acc0 = 0.f, acc1 = 0.f, dh;
    unsigned hoff = 2u*lane;

    if (deg <= 64){
        bool act = lane < deg;
        int sreg = 0;
        float e[8];
        #pragma unroll
        for (int h = 0; h < 8; h++) e[h] = 0.f;
        if (act){
            sreg = col_src[start + lane];
            float4 s0 = *(const float4*)&a_s[sreg*8];
            float4 s1 = *(const float4*)&a_s[sreg*8 + 4];
            float as_[8] = {s0.x,s0.y,s0.z,s0.w,s1.x,s1.y,s1.z,s1.w};
            #pragma unroll
            for (int h = 0; h < 8; h++){
                float v = as_[h] + ad_[h];
                v = v > 0.f ? v : 0.2f*v;
                e[h] = __expf(fminf(v, 70.f));
            }
        }
        #pragma unroll
        for (int h = 0; h < 8; h++) alds[wave][h][lane] = e[h];

        const float* row = &alds[wave][hme][0];
        float s = 0.f;
        #pragma unroll
        for (int j = 0; j < 8; j++) s += row[seg*8 + j];
        s += __shfl_xor(s, 1); s += __shfl_xor(s, 2); s += __shfl_xor(s, 4);
        dh = 1.0f / s;

        int p = 0;
        for (; p + 4 <= deg; p += 4){
            int s0 = __shfl(sreg, p+0), s1 = __shfl(sreg, p+1);
            int s2 = __shfl(sreg, p+2), s3 = __shfl(sreg, p+3);
            unsigned g0 = *(const unsigned*)&H[(size_t)s0*128 + hoff];
            unsigned g1 = *(const unsigned*)&H[(size_t)s1*128 + hoff];
            unsigned g2 = *(const unsigned*)&H[(size_t)s2*128 + hoff];
            unsigned g3 = *(const unsigned*)&H[(size_t)s3*128 + hoff];
            float a0 = row[p+0], a1 = row[p+1], a2 = row[p+2], a3 = row[p+3];
            acc0 += bflo(g0)*a0 + bflo(g1)*a1 + bflo(g2)*a2 + bflo(g3)*a3;
            acc1 += bfhi(g0)*a0 + bfhi(g1)*a1 + bfhi(g2)*a2 + bfhi(g3)*a3;
        }
        for (; p < deg; p++){
            int s0 = __shfl(sreg, p);
            unsigned g0 = *(const unsigned*)&H[(size_t)s0*128 + hoff];
            float a0 = row[p];
            acc0 += bflo(g0)*a0;
            acc1 += bfhi(g0)*a0;
        }
    } else {
        float adh = ad_[hme];
        float s = 0.f;
        for (int p = start + seg; p < end; p += 8){
            int sn = col_src[p];
            float v = a_s[sn*8 + hme] + adh;
            v = v > 0.f ? v : 0.2f*v;
            s += __expf(fminf(v, 70.f));
        }
        s += __shfl_xor(s, 1); s += __shfl_xor(s, 2); s += __shfl_xor(s, 4);
        dh = 1.0f / s;
        for (int p = start; p < end; p++){
            int sn = col_src[p];
            float v = a_s[sn*8 + hme] + adh;
            v = v > 0.f ? v : 0.2f*v;
            float a = __expf(fminf(v, 70.f));
            unsigned g = *(const unsigned*)&H[(size_t)sn*128 + hoff];
            acc0 += bflo(g)*a;
            acc1 += bfhi(g)*a;
        }
    }

    float o0 = acc0*dh + bias[2*lane];
    float o1 = acc1*dh + bias[2*lane + 1];
    o0 = o0 > 0.f ? o0 : expm1f(o0);
    o1 = o1 > 0.f ? o1 : expm1f(o1);
    float2 o = {o0, o1};
    *(float2*)&xout[(size_t)d*HIDDEN + 2*lane] = o;
}

// ---- scores + loss fused ----
__global__ void head_kernel(const float* __restrict__ x, const int* __restrict__ tgt,
                            const float* __restrict__ w, const float* __restrict__ b,
                            float* __restrict__ dout){
    int t = threadIdx.x;   // 64 = BATCH
    const float* row = x + (size_t)tgt[t]*HIDDEN;
    float v = 0.f;
    #pragma unroll
    for (int c = 0; c < HIDDEN; c += 4){
        float4 xv = *(const float4*)&row[c];
        float4 wv = *(const float4*)&w[c];
        v += xv.x*wv.x + xv.y*wv.y + xv.z*wv.z + xv.w*wv.w;
    }
    float sc = v + b[0];
    dout[t] = sc;
    float neg = __shfl(sc, t + 32);
    float dlt = 1.0f - (sc - neg);
    float term = (t < 32) ? (dlt > 0.f ? dlt : 0.f) : 0.f;
    #pragma unroll
    for (int m = 32; m >= 1; m >>= 1) term += __shfl_xor(term, m);
    if (t == 0) dout[BATCH] = term * (1.0f/32.0f);
}

extern "C" void kernel_launch(void* const* d_in, const int* in_sizes, int n_in,
                              void* d_out, int out_size, void* d_ws, size_t ws_size,
                              hipStream_t stream) {
    const float* word   = (const float*)d_in[0];
    const int*   ei     = (const int*)  d_in[1];
    const int*   tgt    = (const int*)  d_in[2];
    const float* lin1W  = (const float*)d_in[4];
    const float* lin1b  = (const float*)d_in[5];
    const float* gatW   = (const float*)d_in[6];
    const float* attS   = (const float*)d_in[7];
    const float* attD   = (const float*)d_in[8];
    const float* gatB   = (const float*)d_in[9];
    const float* lin3W  = (const float*)d_in[10];
    const float* lin3b  = (const float*)d_in[11];

    char* ws = (char*)d_ws;
    size_t off = 0;
    float*   x       = (float*)(ws + off);   off += (size_t)N_NODES*HIDDEN*4;
    bf16_t*  Hb      = (bf16_t*)(ws + off);  off += (size_t)N_NODES*HIDDEN*2;
    float*   a_s     = (float*)(ws + off);   off += (size_t)N_NODES*HEADS*4;
    float*   a_d     = (float*)(ws + off);   off += (size_t)N_NODES*HEADS*4;
    int*     deg     = (int*)(ws + off);     off += (size_t)(N_NODES + 16)*4;
    int*     scantmp = (int*)(ws + off);     off += (size_t)(N_NODES + 16)*4;
    int*     bsums   = (int*)(ws + off);     off += 1024;
    int*     row_ptr = (int*)(ws + off);     off += (size_t)(N_NODES + 16)*4;
    int*     cursor  = (int*)(ws + off);     off += (size_t)(N_NODES + 16)*4;
    int*     col_src = (int*)(ws + off);     off += (size_t)E_TOT*4;
    bf16_t*  b1Hi    = (bf16_t*)(ws + off);  off += (size_t)320*128*2;
    bf16_t*  b1Lo    = (bf16_t*)(ws + off);  off += (size_t)320*128*2;
    bf16_t*  b2Hi    = (bf16_t*)(ws + off);  off += (size_t)128*144*2;
    bf16_t*  b2Lo    = (bf16_t*)(ws + off);  off += (size_t)128*144*2;

    const int NB = (N_NODES + 255)/256;
    const int SB = (N_NODES + 1023)/1024;
    const int GB = ((N_NODES + 15)/16 + 3)/4;   // 782 blocks, 64 rows each
    const int PB = 8*128;                        // partitioned CSR kernels

    // ---- CSR build (once), XCD-partitioned ----
    hipMemsetAsync(deg, 0, (size_t)N_NODES*4, stream);
    deg_part_kernel  <<<PB, 256, 0, stream>>>(ei, deg);
    scan_block_kernel<<<SB, 1024, 0, stream>>>(deg, scantmp, bsums);
    scan_sums_kernel <<<1, 64, 0, stream>>>(bsums, SB);
    scan_add_kernel  <<<NB, 256, 0, stream>>>(scantmp, bsums, row_ptr, cursor);
    scatter_part_kernel<<<PB, 256, 0, stream>>>(ei, cursor, col_src);

    // ---- lin1: x = word @ lin1_W + b ----
    pack_b_kernel<INPUT, 320, 128, false><<<(320*128 + 255)/256, 256, 0, stream>>>(
        lin1W, nullptr, nullptr, b1Hi, b1Lo);
    mfma_gemm4_kernel<INPUT, 8, true, false><<<GB, 256, 0, stream>>>(
        word, b1Hi, b1Lo, lin1b, x, nullptr, nullptr, nullptr, N_NODES);

    for (int L = 0; L < 2; L++){
        const float* W = gatW + (size_t)L*HIDDEN*HIDDEN;
        pack_b_kernel<HIDDEN, 128, 144, true><<<(128*144 + 255)/256, 256, 0, stream>>>(
            W, attS + L*HEADS*HEAD_DIM, attD + L*HEADS*HEAD_DIM, b2Hi, b2Lo);
        mfma_gemm4_kernel<HIDDEN, 9, false, true><<<GB, 256, 0, stream>>>(
            x, b2Hi, b2Lo, nullptr, nullptr, Hb, a_s, a_d, N_NODES);
        gat_aggregate_kernel<<<(N_NODES + 3)/4, 256, 0, stream>>>(
            row_ptr, col_src, (const unsigned short*)Hb, a_s, a_d, gatB + L*HIDDEN, x);
    }

    head_kernel<<<1, 64, 0, stream>>>(x, tgt, lin3W, lin3b, (float*)d_out);
}

// Round 9
// 245.350 us; speedup vs baseline: 1.1309x; 1.1309x over previous
//
#include <hip/hip_runtime.h>
#include <math.h>

#define N_NODES 50000
#define N_EDGESI 800000
#define E_TOT   850000      // + self loops
#define HIDDEN  128
#define HEADS   8
#define HEAD_DIM 16
#define INPUT   300
#define BATCH   64
#define NPART   8
#define PSZ     6250        // N_NODES / NPART

typedef __bf16 bf16_t;
typedef bf16_t bf16x8 __attribute__((ext_vector_type(8)));
typedef float  f32x4  __attribute__((ext_vector_type(4)));

__device__ __forceinline__ float bflo(unsigned u){ return __uint_as_float(u << 16); }
__device__ __forceinline__ float bfhi(unsigned u){ return __uint_as_float(u & 0xffff0000u); }

// ===== pack B (fp32 -> fragment-ready bf16 hi/lo planes) + fused Wa =====
// layout: plane[(k/8)*NCOL*8 + col*8 + (k%8)]
template<int K_REAL, int K_PAD, int NCOL, bool ALPHA>
__global__ void pack_b_kernel(const float* __restrict__ B128, const float* __restrict__ as,
                              const float* __restrict__ ad, bf16_t* __restrict__ bHi,
                              bf16_t* __restrict__ bLo){
    int idx = blockIdx.x*256 + threadIdx.x;
    if (idx >= K_PAD*NCOL) return;
    int k = idx / NCOL, col = idx % NCOL;
    float v = 0.f;
    if (k < K_REAL){
        if (!ALPHA || col < 128){
            v = B128[k*128 + col];
        } else {
            int jj = col - 128;                       // 0..15
            const float* a = (jj < 8) ? (as + jj*16) : (ad + (jj-8)*16);
            const float* wrow = B128 + k*128 + (jj & 7)*16;
            float s = 0.f;
            #pragma unroll
            for (int d = 0; d < 16; d++) s += wrow[d]*a[d];
            v = s;
        }
    }
    bf16_t hi = (bf16_t)v;
    bf16_t lo = (bf16_t)(v - (float)hi);
    int o = ((k >> 3)*NCOL + col)*8 + (k & 7);
    bHi[o] = hi; bLo[o] = lo;
}

// ===== MFMA GEMM v5: B staged in LDS per pass; A via clean register pipeline =====
// one wave = 16 rows x NCOL cols; 4 waves/block = 64 rows.
template<int K_REAL, int K_PAD, int NT, int GH, bool BIAS_EPI, bool ALPHA>
__global__ __launch_bounds__(256)
void mfma_gemm5_kernel(const float* __restrict__ A, const bf16_t* __restrict__ bHi,
                       const bf16_t* __restrict__ bLo, const float* __restrict__ bias,
                       float* __restrict__ outF, bf16_t* __restrict__ outH,
                       float* __restrict__ asrc_out, float* __restrict__ adst_out, int M)
{
    constexpr int NCOL   = NT * 16;
    constexpr int KSTEPS = K_PAD / 32;
    constexpr int KSPP   = GH / 4;            // k-steps per pass
    constexpr int NPASS  = KSTEPS / KSPP;
    constexpr int PD     = 3;                 // A prefetch depth
    constexpr int PELEM  = GH * NCOL * 8;     // elems per plane per pass
    constexpr int SIT    = PELEM / 2048;      // stage iters (256 thr x 8 elems)
    static_assert(KSPP * NPASS == KSTEPS && SIT * 2048 == PELEM, "");
    __shared__ bf16_t bldsH[PELEM];
    __shared__ bf16_t bldsL[PELEM];

    int tid = threadIdx.x, lane = tid & 63, w = tid >> 6;
    int l15 = lane & 15, lg = lane >> 4;
    int m0 = (blockIdx.x*4 + w) * 16;
    int mrow = m0 + l15; if (mrow >= M) mrow = M - 1;   // clamp: stay for barriers
    const float* arow = A + (size_t)mrow*K_REAL;

    // A prefetch prologue (independent of B passes)
    float4 pva[PD], pvb[PD];
    #pragma unroll
    for (int i = 0; i < PD; i++){
        int k0 = i*32 + lg*8;
        pva[i] = (k0 + 3 < K_REAL) ? *(const float4*)&arow[k0]     : (float4){0.f,0.f,0.f,0.f};
        pvb[i] = (k0 + 7 < K_REAL) ? *(const float4*)&arow[k0 + 4] : (float4){0.f,0.f,0.f,0.f};
    }

    f32x4 acc[NT];
    #pragma unroll
    for (int c = 0; c < NT; c++) acc[c] = (f32x4){0.f,0.f,0.f,0.f};

    #pragma unroll
    for (int p = 0; p < NPASS; p++){
        // ---- stage pass p's B chunk into LDS (bulk 16B copies) ----
        const bf16_t* gH = bHi + (size_t)p*PELEM;
        const bf16_t* gL = bLo + (size_t)p*PELEM;
        if (p) __syncthreads();               // previous pass done reading
        #pragma unroll
        for (int it = 0; it < SIT; it++){
            int idx = (tid + it*256)*8;
            *(bf16x8*)&bldsH[idx] = *(const bf16x8*)&gH[idx];
            *(bf16x8*)&bldsL[idx] = *(const bf16x8*)&gL[idx];
        }
        __syncthreads();

        // ---- compute this pass: only vmem in flight = A pipeline ----
        #pragma unroll
        for (int i = 0; i < KSPP; i++){
            const int ks = p*KSPP + i;
            const int sl = ks % PD;
            float4 va = pva[sl], vb = pvb[sl];
            float f[8] = {va.x, va.y, va.z, va.w, vb.x, vb.y, vb.z, vb.w};
            bf16x8 ah, al;
            #pragma unroll
            for (int q = 0; q < 8; q++){
                bf16_t hi = (bf16_t)f[q];
                ah[q] = hi;
                al[q] = (bf16_t)(f[q] - (float)hi);
            }
            if (ks + PD < KSTEPS){            // refill (may cross pass boundary)
                int k0 = (ks + PD)*32 + lg*8;
                pva[sl] = (k0 + 3 < K_REAL) ? *(const float4*)&arow[k0]     : (float4){0.f,0.f,0.f,0.f};
                pvb[sl] = (k0 + 7 < K_REAL) ? *(const float4*)&arow[k0 + 4] : (float4){0.f,0.f,0.f,0.f};
            }
            int gloc = i*4 + lg;
            const bf16_t* bh_base = &bldsH[(gloc*NCOL + l15)*8];
            const bf16_t* bl_base = &bldsL[(gloc*NCOL + l15)*8];
            #pragma unroll
            for (int c = 0; c < NT; c++){
                bf16x8 bh = *(const bf16x8*)&bh_base[c*128];
                bf16x8 bl = *(const bf16x8*)&bl_base[c*128];
                acc[c] = __builtin_amdgcn_mfma_f32_16x16x32_bf16(ah, bh, acc[c], 0,0,0);
                acc[c] = __builtin_amdgcn_mfma_f32_16x16x32_bf16(ah, bl, acc[c], 0,0,0);
                acc[c] = __builtin_amdgcn_mfma_f32_16x16x32_bf16(al, bh, acc[c], 0,0,0);
            }
        }
    }

    // ---- epilogue: D col = lane&15, row = (lane>>4)*4 + reg ----
    #pragma unroll
    for (int c = 0; c < 8; c++){
        int col = c*16 + l15;
        float bv = BIAS_EPI ? bias[col] : 0.f;
        #pragma unroll
        for (int r = 0; r < 4; r++){
            int m = m0 + lg*4 + r;
            if (m < M){
                if (!ALPHA) outF[(size_t)m*128 + col] = acc[c][r] + bv;
                else        outH[(size_t)m*128 + col] = (bf16_t)acc[c][r];
            }
        }
    }
    if (ALPHA){
        #pragma unroll
        for (int r = 0; r < 4; r++){
            int m = m0 + lg*4 + r;
            if (m < M){
                float v = acc[8][r];
                if (l15 < 8) asrc_out[m*8 + l15]       = v;
                else         adst_out[m*8 + (l15 - 8)] = v;
            }
        }
    }
}

// ============== CSR build, XCD-partitioned by dst range ==============
__global__ __launch_bounds__(256)
void deg_part_kernel(const int* __restrict__ ei, int* __restrict__ deg){
    int part = blockIdx.x & 7;
    int bwp  = blockIdx.x >> 3;
    int nbp  = gridDim.x >> 3;
    int lo = part*PSZ, hi = lo + PSZ;
    for (int e = bwp*256 + threadIdx.x; e < E_TOT; e += nbp*256){
        int d = (e < N_EDGESI) ? ei[N_EDGESI + e] : (e - N_EDGESI);
        if (d >= lo && d < hi) atomicAdd(&deg[d], 1);
    }
}

__global__ __launch_bounds__(256)
void scatter_part_kernel(const int* __restrict__ ei, int* __restrict__ cursor,
                         int* __restrict__ col_src){
    int part = blockIdx.x & 7;
    int bwp  = blockIdx.x >> 3;
    int nbp  = gridDim.x >> 3;
    int lo = part*PSZ, hi = lo + PSZ;
    for (int e = bwp*256 + threadIdx.x; e < E_TOT; e += nbp*256){
        int d = (e < N_EDGESI) ? ei[N_EDGESI + e] : (e - N_EDGESI);
        if (d >= lo && d < hi){
            int s = (e < N_EDGESI) ? ei[e] : d;
            int pos = atomicAdd(&cursor[d], 1);
            col_src[pos] = s;
        }
    }
}

__global__ void scan_block_kernel(const int* __restrict__ deg, int* __restrict__ scanout,
                                  int* __restrict__ blocksums){
    __shared__ int buf[1024];
    int gid = blockIdx.x*1024 + threadIdx.x;
    int v = (gid < N_NODES) ? deg[gid] : 0;
    buf[threadIdx.x] = v;
    __syncthreads();
    for (int off = 1; off < 1024; off <<= 1){
        int t = (threadIdx.x >= off) ? buf[threadIdx.x - off] : 0;
        __syncthreads();
        buf[threadIdx.x] += t;
        __syncthreads();
    }
    if (gid < N_NODES) scanout[gid] = buf[threadIdx.x] - v;   // exclusive
    if (threadIdx.x == 1023) blocksums[blockIdx.x] = buf[1023];
}

// wave-parallel exclusive scan of <=64 block sums
__global__ void scan_sums_kernel(int* __restrict__ blocksums, int nb){
    int t = threadIdx.x;   // 64
    int orig = (t < nb) ? blocksums[t] : 0;
    int v = orig;
    #pragma unroll
    for (int off = 1; off < 64; off <<= 1){
        int u = __shfl_up(v, off);
        if (t >= off) v += u;
    }
    if (t < nb) blocksums[t] = v - orig;   // exclusive
}

__global__ void scan_add_kernel(const int* __restrict__ scanout, const int* __restrict__ blocksums,
                                int* __restrict__ row_ptr, int* __restrict__ cursor){
    int i = blockIdx.x*256 + threadIdx.x;
    if (i < N_NODES){
        int v = scanout[i] + blocksums[i >> 10];
        row_ptr[i] = v;
        cursor[i]  = v;
    }
    if (i == 0) row_ptr[N_NODES] = E_TOT;
}

// ===== fused per-dst softmax + aggregate + bias + ELU: one wave per node =====
__global__ __launch_bounds__(256)
void gat_aggregate_kernel(const int* __restrict__ row_ptr, const int* __restrict__ col_src,
                          const unsigned short* __restrict__ H, const float* __restrict__ a_s,
                          const float* __restrict__ a_d, const float* __restrict__ bias,
                          float* __restrict__ xout){
    __shared__ float alds[4][8][65];
    int wave = threadIdx.x >> 6;
    int lane = threadIdx.x & 63;
    int d = blockIdx.x*4 + wave;
    if (d >= N_NODES) return;
    int start = row_ptr[d], end = row_ptr[d + 1];
    int deg = end - start;                 // >= 1 (self loop)
    int hme = lane >> 3, seg = lane & 7;

    float ad_[8];
    {
        float4 t0 = *(const float4*)&a_d[d*8];
        float4 t1 = *(const float4*)&a_d[d*8 + 4];
        ad_[0]=t0.x; ad_[1]=t0.y; ad_[2]=t0.z; ad_[3]=t0.w;
        ad_[4]=t1.x; ad_[5]=t1.y; ad_[6]=t1.z; ad_[7]=t1.w;
    }

    float acc0 = 0.f, acc1 = 0.f, dh;
    unsigned hoff = 2u*lane;

    if (deg <= 64){
        bool act = lane < deg;
        int sreg = 0;
        float e[8];
        #pragma unroll
        for (int h = 0; h < 8; h++) e[h] = 0.f;
        if (act){
            sreg = col_src[start + lane];
            float4 s0 = *(const float4*)&a_s[sreg*8];
            float4 s1 = *(const float4*)&a_s[sreg*8 + 4];
            float as_[8] = {s0.x,s0.y,s0.z,s0.w,s1.x,s1.y,s1.z,s1.w};
            #pragma unroll
            for (int h = 0; h < 8; h++){
                float v = as_[h] + ad_[h];
                v = v > 0.f ? v : 0.2f*v;
                e[h] = __expf(fminf(v, 70.f));
            }
        }
        #pragma unroll
        for (int h = 0; h < 8; h++) alds[wave][h][lane] = e[h];

        const float* row = &alds[wave][hme][0];
        float s = 0.f;
        #pragma unroll
        for (int j = 0; j < 8; j++) s += row[seg*8 + j];
        s += __shfl_xor(s, 1); s += __shfl_xor(s, 2); s += __shfl_xor(s, 4);
        dh = 1.0f / s;

        int p = 0;
        for (; p + 4 <= deg; p += 4){
            int s0 = __shfl(sreg, p+0), s1 = __shfl(sreg, p+1);
            int s2 = __shfl(sreg, p+2), s3 = __shfl(sreg, p+3);
            unsigned g0 = *(const unsigned*)&H[(size_t)s0*128 + hoff];
            unsigned g1 = *(const unsigned*)&H[(size_t)s1*128 + hoff];
            unsigned g2 = *(const unsigned*)&H[(size_t)s2*128 + hoff];
            unsigned g3 = *(const unsigned*)&H[(size_t)s3*128 + hoff];
            float a0 = row[p+0], a1 = row[p+1], a2 = row[p+2], a3 = row[p+3];
            acc0 += bflo(g0)*a0 + bflo(g1)*a1 + bflo(g2)*a2 + bflo(g3)*a3;
            acc1 += bfhi(g0)*a0 + bfhi(g1)*a1 + bfhi(g2)*a2 + bfhi(g3)*a3;
        }
        for (; p < deg; p++){
            int s0 = __shfl(sreg, p);
            unsigned g0 = *(const unsigned*)&H[(size_t)s0*128 + hoff];
            float a0 = row[p];
            acc0 += bflo(g0)*a0;
            acc1 += bfhi(g0)*a0;
        }
    } else {
        float adh = ad_[hme];
        float s = 0.f;
        for (int p = start + seg; p < end; p += 8){
            int sn = col_src[p];
            float v = a_s[sn*8 + hme] + adh;
            v = v > 0.f ? v : 0.2f*v;
            s += __expf(fminf(v, 70.f));
        }
        s += __shfl_xor(s, 1); s += __shfl_xor(s, 2); s += __shfl_xor(s, 4);
        dh = 1.0f / s;
        for (int p = start; p < end; p++){
            int sn = col_src[p];
            float v = a_s[sn*8 + hme] + adh;
            v = v > 0.f ? v : 0.2f*v;
            float a = __expf(fminf(v, 70.f));
            unsigned g = *(const unsigned*)&H[(size_t)sn*128 + hoff];
            acc0 += bflo(g)*a;
            acc1 += bfhi(g)*a;
        }
    }

    float o0 = acc0*dh + bias[2*lane];
    float o1 = acc1*dh + bias[2*lane + 1];
    o0 = o0 > 0.f ? o0 : expm1f(o0);
    o1 = o1 > 0.f ? o1 : expm1f(o1);
    float2 o = {o0, o1};
    *(float2*)&xout[(size_t)d*HIDDEN + 2*lane] = o;
}

// ---- scores + loss fused ----
__global__ void head_kernel(const float* __restrict__ x, const int* __restrict__ tgt,
                            const float* __restrict__ w, const float* __restrict__ b,
                            float* __restrict__ dout){
    int t = threadIdx.x;   // 64 = BATCH
    const float* row = x + (size_t)tgt[t]*HIDDEN;
    float v = 0.f;
    #pragma unroll
    for (int c = 0; c < HIDDEN; c += 4){
        float4 xv = *(const float4*)&row[c];
        float4 wv = *(const float4*)&w[c];
        v += xv.x*wv.x + xv.y*wv.y + xv.z*wv.z + xv.w*wv.w;
    }
    float sc = v + b[0];
    dout[t] = sc;
    float neg = __shfl(sc, t + 32);
    float dlt = 1.0f - (sc - neg);
    float term = (t < 32) ? (dlt > 0.f ? dlt : 0.f) : 0.f;
    #pragma unroll
    for (int m = 32; m >= 1; m >>= 1) term += __shfl_xor(term, m);
    if (t == 0) dout[BATCH] = term * (1.0f/32.0f);
}

extern "C" void kernel_launch(void* const* d_in, const int* in_sizes, int n_in,
                              void* d_out, int out_size, void* d_ws, size_t ws_size,
                              hipStream_t stream) {
    const float* word   = (const float*)d_in[0];
    const int*   ei     = (const int*)  d_in[1];
    const int*   tgt    = (const int*)  d_in[2];
    const float* lin1W  = (const float*)d_in[4];
    const float* lin1b  = (const float*)d_in[5];
    const float* gatW   = (const float*)d_in[6];
    const float* attS   = (const float*)d_in[7];
    const float* attD   = (const float*)d_in[8];
    const float* gatB   = (const float*)d_in[9];
    const float* lin3W  = (const float*)d_in[10];
    const float* lin3b  = (const float*)d_in[11];

    char* ws = (char*)d_ws;
    size_t off = 0;
    float*   x       = (float*)(ws + off);   off += (size_t)N_NODES*HIDDEN*4;
    bf16_t*  Hb      = (bf16_t*)(ws + off);  off += (size_t)N_NODES*HIDDEN*2;
    float*   a_s     = (float*)(ws + off);   off += (size_t)N_NODES*HEADS*4;
    float*   a_d     = (float*)(ws + off);   off += (size_t)N_NODES*HEADS*4;
    int*     deg     = (int*)(ws + off);     off += (size_t)(N_NODES + 16)*4;
    int*     scantmp = (int*)(ws + off);     off += (size_t)(N_NODES + 16)*4;
    int*     bsums   = (int*)(ws + off);     off += 1024;
    int*     row_ptr = (int*)(ws + off);     off += (size_t)(N_NODES + 16)*4;
    int*     cursor  = (int*)(ws + off);     off += (size_t)(N_NODES + 16)*4;
    int*     col_src = (int*)(ws + off);     off += (size_t)E_TOT*4;
    bf16_t*  b1Hi    = (bf16_t*)(ws + off);  off += (size_t)320*128*2;
    bf16_t*  b1Lo    = (bf16_t*)(ws + off);  off += (size_t)320*128*2;
    bf16_t*  b2Hi    = (bf16_t*)(ws + off);  off += (size_t)128*144*2;
    bf16_t*  b2Lo    = (bf16_t*)(ws + off);  off += (size_t)128*144*2;

    const int NB = (N_NODES + 255)/256;
    const int SB = (N_NODES + 1023)/1024;
    const int GB = ((N_NODES + 15)/16 + 3)/4;   // 782 blocks, 64 rows each
    const int PB = 8*128;                        // partitioned CSR kernels

    // ---- CSR build (once), XCD-partitioned ----
    hipMemsetAsync(deg, 0, (size_t)N_NODES*4, stream);
    deg_part_kernel  <<<PB, 256, 0, stream>>>(ei, deg);
    scan_block_kernel<<<SB, 1024, 0, stream>>>(deg, scantmp, bsums);
    scan_sums_kernel <<<1, 64, 0, stream>>>(bsums, SB);
    scan_add_kernel  <<<NB, 256, 0, stream>>>(scantmp, bsums, row_ptr, cursor);
    scatter_part_kernel<<<PB, 256, 0, stream>>>(ei, cursor, col_src);

    // ---- lin1: x = word @ lin1_W + b ----
    pack_b_kernel<INPUT, 320, 128, false><<<(320*128 + 255)/256, 256, 0, stream>>>(
        lin1W, nullptr, nullptr, b1Hi, b1Lo);
    mfma_gemm5_kernel<INPUT, 320, 8, 20, true, false><<<GB, 256, 0, stream>>>(
        word, b1Hi, b1Lo, lin1b, x, nullptr, nullptr, nullptr, N_NODES);

    for (int L = 0; L < 2; L++){
        const float* W = gatW + (size_t)L*HIDDEN*HIDDEN;
        pack_b_kernel<HIDDEN, 128, 144, true><<<(128*144 + 255)/256, 256, 0, stream>>>(
            W, attS + L*HEADS*HEAD_DIM, attD + L*HEADS*HEAD_DIM, b2Hi, b2Lo);
        mfma_gemm5_kernel<HIDDEN, 128, 9, 16, false, true><<<GB, 256, 0, stream>>>(
            x, b2Hi, b2Lo, nullptr, nullptr, Hb, a_s, a_d, N_NODES);
        gat_aggregate_kernel<<<(N_NODES + 3)/4, 256, 0, stream>>>(
            row_ptr, col_src, (const unsigned short*)Hb, a_s, a_d, gatB + L*HIDDEN, x);
    }

    head_kernel<<<1, 64, 0, stream>>>(x, tgt, lin3W, lin3b, (float*)d_out);
}

// Round 10
// 234.460 us; speedup vs baseline: 1.1834x; 1.0464x over previous
//
#include <hip/hip_runtime.h>
#include <math.h>

#define N_NODES 50000
#define N_EDGESI 800000
#define E_TOT   850000      // + self loops
#define HIDDEN  128
#define HEADS   8
#define HEAD_DIM 16
#define INPUT   300
#define BATCH   64
#define NPART   8
#define PSZ     6250        // N_NODES / NPART

typedef __bf16 bf16_t;
typedef bf16_t bf16x8 __attribute__((ext_vector_type(8)));
typedef bf16_t bf16x2 __attribute__((ext_vector_type(2)));
typedef float  f32x4  __attribute__((ext_vector_type(4)));

__device__ __forceinline__ float bflo(unsigned u){ return __uint_as_float(u << 16); }
__device__ __forceinline__ float bfhi(unsigned u){ return __uint_as_float(u & 0xffff0000u); }

// ===== pack B (fp32 -> fragment-ready bf16 plane) + fused Wa =====
// layout: plane[(k/8)*NCOL*8 + col*8 + (k%8)]
template<int K_REAL, int K_PAD, int NCOL, bool ALPHA>
__global__ void pack_b_kernel(const float* __restrict__ B128, const float* __restrict__ as,
                              const float* __restrict__ ad, bf16_t* __restrict__ bHi){
    int idx = blockIdx.x*256 + threadIdx.x;
    if (idx >= K_PAD*NCOL) return;
    int k = idx / NCOL, col = idx % NCOL;
    float v = 0.f;
    if (k < K_REAL){
        if (!ALPHA || col < 128){
            v = B128[k*128 + col];
        } else {
            int jj = col - 128;                       // 0..15
            const float* a = (jj < 8) ? (as + jj*16) : (ad + (jj-8)*16);
            const float* wrow = B128 + k*128 + (jj & 7)*16;
            float s = 0.f;
            #pragma unroll
            for (int d = 0; d < 16; d++) s += wrow[d]*a[d];
            v = s;
        }
    }
    int o = ((k >> 3)*NCOL + col)*8 + (k & 7);
    bHi[o] = (bf16_t)v;
}

// ===== MFMA GEMM v6: single bf16, B staged in LDS, deep A register prefetch =====
// one wave = 16 rows x NCOL cols; 4 waves/block = 64 rows.
template<int K_REAL, int K_PAD, int NT, int GH, int PD, bool A_BF16, bool BIAS_EPI, bool ALPHA>
__global__ __launch_bounds__(256)
void mfma_gemm6_kernel(const void* __restrict__ A_, const bf16_t* __restrict__ bHi,
                       const float* __restrict__ bias, bf16_t* __restrict__ outH,
                       float* __restrict__ asrc_out, float* __restrict__ adst_out, int M)
{
    constexpr int NCOL   = NT * 16;
    constexpr int KSTEPS = K_PAD / 32;
    constexpr int KSPP   = GH / 4;            // k-steps per pass
    constexpr int NPASS  = KSTEPS / KSPP;
    constexpr int PELEM  = GH * NCOL * 8;     // bf16 elems per pass
    constexpr int SIT    = PELEM / 2048;      // stage iters (256 thr x 8 elems)
    static_assert(KSPP * NPASS == KSTEPS && SIT * 2048 == PELEM, "");
    __shared__ bf16_t blds[PELEM];

    int tid = threadIdx.x, lane = tid & 63, w = tid >> 6;
    int l15 = lane & 15, lg = lane >> 4;
    int m0 = (blockIdx.x*4 + w) * 16;
    int mrow = m0 + l15; if (mrow >= M) mrow = M - 1;   // clamp: stay for barriers

    const float*  arowF = (const float*) A_ + (size_t)mrow*K_REAL;
    const bf16_t* arowB = (const bf16_t*)A_ + (size_t)mrow*K_REAL;

    // ---- A prefetch prologue ----
    float4 pva[PD], pvb[PD];
    bf16x8 pab[PD];
    #pragma unroll
    for (int i = 0; i < PD; i++){
        int k0 = i*32 + lg*8;
        if (A_BF16){
            pab[i] = *(const bf16x8*)&arowB[k0];
        } else {
            pva[i] = (k0 + 3 < K_REAL) ? *(const float4*)&arowF[k0]     : (float4){0.f,0.f,0.f,0.f};
            pvb[i] = (k0 + 7 < K_REAL) ? *(const float4*)&arowF[k0 + 4] : (float4){0.f,0.f,0.f,0.f};
        }
    }

    f32x4 acc[NT];
    #pragma unroll
    for (int c = 0; c < NT; c++) acc[c] = (f32x4){0.f,0.f,0.f,0.f};

    #pragma unroll
    for (int p = 0; p < NPASS; p++){
        // ---- stage pass p's B chunk into LDS ----
        const bf16_t* gB = bHi + (size_t)p*PELEM;
        if (p) __syncthreads();
        #pragma unroll
        for (int it = 0; it < SIT; it++){
            int idx = (tid + it*256)*8;
            *(bf16x8*)&blds[idx] = *(const bf16x8*)&gB[idx];
        }
        __syncthreads();

        #pragma unroll
        for (int i = 0; i < KSPP; i++){
            const int ks = p*KSPP + i;
            const int sl = ks % PD;
            bf16x8 ah;
            if (A_BF16){
                ah = pab[sl];
            } else {
                float4 va = pva[sl], vb = pvb[sl];
                float f[8] = {va.x, va.y, va.z, va.w, vb.x, vb.y, vb.z, vb.w};
                #pragma unroll
                for (int q = 0; q < 8; q++) ah[q] = (bf16_t)f[q];
            }
            if (ks + PD < KSTEPS){            // refill
                int k0 = (ks + PD)*32 + lg*8;
                if (A_BF16){
                    pab[sl] = *(const bf16x8*)&arowB[k0];
                } else {
                    pva[sl] = (k0 + 3 < K_REAL) ? *(const float4*)&arowF[k0]     : (float4){0.f,0.f,0.f,0.f};
                    pvb[sl] = (k0 + 7 < K_REAL) ? *(const float4*)&arowF[k0 + 4] : (float4){0.f,0.f,0.f,0.f};
                }
            }
            int gloc = i*4 + lg;
            const bf16_t* b_base = &blds[(gloc*NCOL + l15)*8];
            #pragma unroll
            for (int c = 0; c < NT; c++){
                bf16x8 bh = *(const bf16x8*)&b_base[c*128];
                acc[c] = __builtin_amdgcn_mfma_f32_16x16x32_bf16(ah, bh, acc[c], 0,0,0);
            }
        }
    }

    // ---- epilogue: D col = lane&15, row = (lane>>4)*4 + reg; bf16 out ----
    #pragma unroll
    for (int c = 0; c < 8; c++){
        int col = c*16 + l15;
        float bv = BIAS_EPI ? bias[col] : 0.f;
        #pragma unroll
        for (int r = 0; r < 4; r++){
            int m = m0 + lg*4 + r;
            if (m < M) outH[(size_t)m*128 + col] = (bf16_t)(acc[c][r] + bv);
        }
    }
    if (ALPHA){
        #pragma unroll
        for (int r = 0; r < 4; r++){
            int m = m0 + lg*4 + r;
            if (m < M){
                float v = acc[8][r];
                if (l15 < 8) asrc_out[m*8 + l15]       = v;
                else         adst_out[m*8 + (l15 - 8)] = v;
            }
        }
    }
}

// ============== CSR build, XCD-partitioned by dst range ==============
__global__ __launch_bounds__(256)
void deg_part_kernel(const int* __restrict__ ei, int* __restrict__ deg){
    int part = blockIdx.x & 7;
    int bwp  = blockIdx.x >> 3;
    int nbp  = gridDim.x >> 3;
    int lo = part*PSZ, hi = lo + PSZ;
    for (int e = bwp*256 + threadIdx.x; e < E_TOT; e += nbp*256){
        int d = (e < N_EDGESI) ? ei[N_EDGESI + e] : (e - N_EDGESI);
        if (d >= lo && d < hi) atomicAdd(&deg[d], 1);
    }
}

__global__ __launch_bounds__(256)
void scatter_part_kernel(const int* __restrict__ ei, int* __restrict__ cursor,
                         int* __restrict__ col_src){
    int part = blockIdx.x & 7;
    int bwp  = blockIdx.x >> 3;
    int nbp  = gridDim.x >> 3;
    int lo = part*PSZ, hi = lo + PSZ;
    for (int e = bwp*256 + threadIdx.x; e < E_TOT; e += nbp*256){
        int d = (e < N_EDGESI) ? ei[N_EDGESI + e] : (e - N_EDGESI);
        if (d >= lo && d < hi){
            int s = (e < N_EDGESI) ? ei[e] : d;
            int pos = atomicAdd(&cursor[d], 1);
            col_src[pos] = s;
        }
    }
}

__global__ void scan_block_kernel(const int* __restrict__ deg, int* __restrict__ scanout,
                                  int* __restrict__ blocksums){
    __shared__ int buf[1024];
    int gid = blockIdx.x*1024 + threadIdx.x;
    int v = (gid < N_NODES) ? deg[gid] : 0;
    buf[threadIdx.x] = v;
    __syncthreads();
    for (int off = 1; off < 1024; off <<= 1){
        int t = (threadIdx.x >= off) ? buf[threadIdx.x - off] : 0;
        __syncthreads();
        buf[threadIdx.x] += t;
        __syncthreads();
    }
    if (gid < N_NODES) scanout[gid] = buf[threadIdx.x] - v;   // exclusive
    if (threadIdx.x == 1023) blocksums[blockIdx.x] = buf[1023];
}

// wave-parallel exclusive scan of <=64 block sums
__global__ void scan_sums_kernel(int* __restrict__ blocksums, int nb){
    int t = threadIdx.x;   // 64
    int orig = (t < nb) ? blocksums[t] : 0;
    int v = orig;
    #pragma unroll
    for (int off = 1; off < 64; off <<= 1){
        int u = __shfl_up(v, off);
        if (t >= off) v += u;
    }
    if (t < nb) blocksums[t] = v - orig;   // exclusive
}

__global__ void scan_add_kernel(const int* __restrict__ scanout, const int* __restrict__ blocksums,
                                int* __restrict__ row_ptr, int* __restrict__ cursor){
    int i = blockIdx.x*256 + threadIdx.x;
    if (i < N_NODES){
        int v = scanout[i] + blocksums[i >> 10];
        row_ptr[i] = v;
        cursor[i]  = v;
    }
    if (i == 0) row_ptr[N_NODES] = E_TOT;
}

// ===== fused per-dst softmax + aggregate + bias + ELU: one wave per node =====
__global__ __launch_bounds__(256)
void gat_aggregate_kernel(const int* __restrict__ row_ptr, const int* __restrict__ col_src,
                          const unsigned short* __restrict__ H, const float* __restrict__ a_s,
                          const float* __restrict__ a_d, const float* __restrict__ bias,
                          bf16_t* __restrict__ xout){
    __shared__ float alds[4][8][65];
    int wave = threadIdx.x >> 6;
    int lane = threadIdx.x & 63;
    int d = blockIdx.x*4 + wave;
    if (d >= N_NODES) return;
    int start = row_ptr[d], end = row_ptr[d + 1];
    int deg = end - start;                 // >= 1 (self loop)
    int hme = lane >> 3, seg = lane & 7;

    float ad_[8];
    {
        float4 t0 = *(const float4*)&a_d[d*8];
        float4 t1 = *(const float4*)&a_d[d*8 + 4];
        ad_[0]=t0.x; ad_[1]=t0.y; ad_[2]=t0.z; ad_[3]=t0.w;
        ad_[4]=t1.x; ad_[5]=t1.y; ad_[6]=t1.z; ad_[7]=t1.w;
    }

    float acc0 = 0.f, acc1 = 0.f, dh;
    unsigned hoff = 2u*lane;

    if (deg <= 64){
        bool act = lane < deg;
        int sreg = 0;
        float e[8];
        #pragma unroll
        for (int h = 0; h < 8; h++) e[h] = 0.f;
        if (act){
            sreg = col_src[start + lane];
            float4 s0 = *(const float4*)&a_s[sreg*8];
            float4 s1 = *(const float4*)&a_s[sreg*8 + 4];
            float as_[8] = {s0.x,s0.y,s0.z,s0.w,s1.x,s1.y,s1.z,s1.w};
            #pragma unroll
            for (int h = 0; h < 8; h++){
                float v = as_[h] + ad_[h];
                v = v > 0.f ? v : 0.2f*v;
                e[h] = __expf(fminf(v, 70.f));
            }
        }
        #pragma unroll
        for (int h = 0; h < 8; h++) alds[wave][h][lane] = e[h];

        const float* row = &alds[wave][hme][0];
        float s = 0.f;
        #pragma unroll
        for (int j = 0; j < 8; j++) s += row[seg*8 + j];
        s += __shfl_xor(s, 1); s += __shfl_xor(s, 2); s += __shfl_xor(s, 4);
        dh = 1.0f / s;

        int p = 0;
        for (; p + 4 <= deg; p += 4){
            int s0 = __shfl(sreg, p+0), s1 = __shfl(sreg, p+1);
            int s2 = __shfl(sreg, p+2), s3 = __shfl(sreg, p+3);
            unsigned g0 = *(const unsigned*)&H[(size_t)s0*128 + hoff];
            unsigned g1 = *(const unsigned*)&H[(size_t)s1*128 + hoff];
            unsigned g2 = *(const unsigned*)&H[(size_t)s2*128 + hoff];
            unsigned g3 = *(const unsigned*)&H[(size_t)s3*128 + hoff];
            float a0 = row[p+0], a1 = row[p+1], a2 = row[p+2], a3 = row[p+3];
            acc0 += bflo(g0)*a0 + bflo(g1)*a1 + bflo(g2)*a2 + bflo(g3)*a3;
            acc1 += bfhi(g0)*a0 + bfhi(g1)*a1 + bfhi(g2)*a2 + bfhi(g3)*a3;
        }
        for (; p < deg; p++){
            int s0 = __shfl(sreg, p);
            unsigned g0 = *(const unsigned*)&H[(size_t)s0*128 + hoff];
            float a0 = row[p];
            acc0 += bflo(g0)*a0;
            acc1 += bfhi(g0)*a0;
        }
    } else {
        float adh = ad_[hme];
        float s = 0.f;
        for (int p = start + seg; p < end; p += 8){
            int sn = col_src[p];
            float v = a_s[sn*8 + hme] + adh;
            v = v > 0.f ? v : 0.2f*v;
            s += __expf(fminf(v, 70.f));
        }
        s += __shfl_xor(s, 1); s += __shfl_xor(s, 2); s += __shfl_xor(s, 4);
        dh = 1.0f / s;
        for (int p = start; p < end; p++){
            int sn = col_src[p];
            float v = a_s[sn*8 + hme] + adh;
            v = v > 0.f ? v : 0.2f*v;
            float a = __expf(fminf(v, 70.f));
            unsigned g = *(const unsigned*)&H[(size_t)sn*128 + hoff];
            acc0 += bflo(g)*a;
            acc1 += bfhi(g)*a;
        }
    }

    float o0 = acc0*dh + bias[2*lane];
    float o1 = acc1*dh + bias[2*lane + 1];
    o0 = o0 > 0.f ? o0 : expm1f(o0);
    o1 = o1 > 0.f ? o1 : expm1f(o1);
    bf16x2 o = {(bf16_t)o0, (bf16_t)o1};
    *(bf16x2*)&xout[(size_t)d*HIDDEN + 2*lane] = o;
}

// ---- scores + loss fused ----
__global__ void head_kernel(const bf16_t* __restrict__ x, const int* __restrict__ tgt,
                            const float* __restrict__ w, const float* __restrict__ b,
                            float* __restrict__ dout){
    int t = threadIdx.x;   // 64 = BATCH
    const bf16_t* row = x + (size_t)tgt[t]*HIDDEN;
    float v = 0.f;
    #pragma unroll
    for (int c = 0; c < HIDDEN; c += 8){
        bf16x8 xv = *(const bf16x8*)&row[c];
        #pragma unroll
        for (int j = 0; j < 8; j++) v += (float)xv[j] * w[c + j];
    }
    float sc = v + b[0];
    dout[t] = sc;
    float neg = __shfl(sc, t + 32);
    float dlt = 1.0f - (sc - neg);
    float term = (t < 32) ? (dlt > 0.f ? dlt : 0.f) : 0.f;
    #pragma unroll
    for (int m = 32; m >= 1; m >>= 1) term += __shfl_xor(term, m);
    if (t == 0) dout[BATCH] = term * (1.0f/32.0f);
}

extern "C" void kernel_launch(void* const* d_in, const int* in_sizes, int n_in,
                              void* d_out, int out_size, void* d_ws, size_t ws_size,
                              hipStream_t stream) {
    const float* word   = (const float*)d_in[0];
    const int*   ei     = (const int*)  d_in[1];
    const int*   tgt    = (const int*)  d_in[2];
    const float* lin1W  = (const float*)d_in[4];
    const float* lin1b  = (const float*)d_in[5];
    const float* gatW   = (const float*)d_in[6];
    const float* attS   = (const float*)d_in[7];
    const float* attD   = (const float*)d_in[8];
    const float* gatB   = (const float*)d_in[9];
    const float* lin3W  = (const float*)d_in[10];
    const float* lin3b  = (const float*)d_in[11];

    char* ws = (char*)d_ws;
    size_t off = 0;
    bf16_t*  Xb      = (bf16_t*)(ws + off);  off += (size_t)N_NODES*HIDDEN*2;
    bf16_t*  Hb      = (bf16_t*)(ws + off);  off += (size_t)N_NODES*HIDDEN*2;
    float*   a_s     = (float*)(ws + off);   off += (size_t)N_NODES*HEADS*4;
    float*   a_d     = (float*)(ws + off);   off += (size_t)N_NODES*HEADS*4;
    int*     deg     = (int*)(ws + off);     off += (size_t)(N_NODES + 16)*4;
    int*     scantmp = (int*)(ws + off);     off += (size_t)(N_NODES + 16)*4;
    int*     bsums   = (int*)(ws + off);     off += 1024;
    int*     row_ptr = (int*)(ws + off);     off += (size_t)(N_NODES + 16)*4;
    int*     cursor  = (int*)(ws + off);     off += (size_t)(N_NODES + 16)*4;
    int*     col_src = (int*)(ws + off);     off += (size_t)E_TOT*4;
    bf16_t*  b1      = (bf16_t*)(ws + off);  off += (size_t)320*128*2;
    bf16_t*  b2      = (bf16_t*)(ws + off);  off += (size_t)128*144*2;

    const int NB = (N_NODES + 255)/256;
    const int SB = (N_NODES + 1023)/1024;
    const int GB = ((N_NODES + 15)/16 + 3)/4;   // 782 blocks, 64 rows each
    const int PB = 8*128;                        // partitioned CSR kernels

    // ---- CSR build (once), XCD-partitioned ----
    hipMemsetAsync(deg, 0, (size_t)N_NODES*4, stream);
    deg_part_kernel  <<<PB, 256, 0, stream>>>(ei, deg);
    scan_block_kernel<<<SB, 1024, 0, stream>>>(deg, scantmp, bsums);
    scan_sums_kernel <<<1, 64, 0, stream>>>(bsums, SB);
    scan_add_kernel  <<<NB, 256, 0, stream>>>(scantmp, bsums, row_ptr, cursor);
    scatter_part_kernel<<<PB, 256, 0, stream>>>(ei, cursor, col_src);

    // ---- lin1: Xb = bf16(word @ lin1_W + b) ----
    pack_b_kernel<INPUT, 320, 128, false><<<(320*128 + 255)/256, 256, 0, stream>>>(
        lin1W, nullptr, nullptr, b1);
    mfma_gemm6_kernel<INPUT, 320, 8, 20, 5, false, true, false><<<GB, 256, 0, stream>>>(
        word, b1, lin1b, Xb, nullptr, nullptr, N_NODES);

    for (int L = 0; L < 2; L++){
        const float* W = gatW + (size_t)L*HIDDEN*HIDDEN;
        pack_b_kernel<HIDDEN, 128, 144, true><<<(128*144 + 255)/256, 256, 0, stream>>>(
            W, attS + L*HEADS*HEAD_DIM, attD + L*HEADS*HEAD_DIM, b2);
        mfma_gemm6_kernel<HIDDEN, 128, 9, 16, 4, true, false, true><<<GB, 256, 0, stream>>>(
            Xb, b2, nullptr, Hb, a_s, a_d, N_NODES);
        gat_aggregate_kernel<<<(N_NODES + 3)/4, 256, 0, stream>>>(
            row_ptr, col_src, (const unsigned short*)Hb, a_s, a_d, gatB + L*HIDDEN, Xb);
    }

    head_kernel<<<1, 64, 0, stream>>>(Xb, tgt, lin3W, lin3b, (float*)d_out);
}

// Round 12
// 226.119 us; speedup vs baseline: 1.2271x; 1.0369x over previous
//
#include <hip/hip_runtime.h>
#include <math.h>

#define N_NODES 50000
#define N_EDGESI 800000
#define E_TOT   850000      // + self loops
#define HIDDEN  128
#define HEADS   8
#define HEAD_DIM 16
#define INPUT   300
#define BATCH   64
#define NPART   8
#define PSZ     6250        // N_NODES / NPART

typedef __bf16 bf16_t;
typedef bf16_t bf16x8 __attribute__((ext_vector_type(8)));
typedef bf16_t bf16x2 __attribute__((ext_vector_type(2)));
typedef float  f32x4  __attribute__((ext_vector_type(4)));

__device__ __forceinline__ float bflo(unsigned u){ return __uint_as_float(u << 16); }
__device__ __forceinline__ float bfhi(unsigned u){ return __uint_as_float(u & 0xffff0000u); }

// ===== pack B (fp32 -> fragment-ready bf16 plane) + fused Wa =====
template<int K_REAL, int K_PAD, int NCOL, bool ALPHA>
__global__ void pack_b_kernel(const float* __restrict__ B128, const float* __restrict__ as,
                              const float* __restrict__ ad, bf16_t* __restrict__ bHi){
    int idx = blockIdx.x*256 + threadIdx.x;
    if (idx >= K_PAD*NCOL) return;
    int k = idx / NCOL, col = idx % NCOL;
    float v = 0.f;
    if (k < K_REAL){
        if (!ALPHA || col < 128){
            v = B128[k*128 + col];
        } else {
            int jj = col - 128;                       // 0..15
            const float* a = (jj < 8) ? (as + jj*16) : (ad + (jj-8)*16);
            const float* wrow = B128 + k*128 + (jj & 7)*16;
            float s = 0.f;
            #pragma unroll
            for (int d = 0; d < 16; d++) s += wrow[d]*a[d];
            v = s;
        }
    }
    int o = ((k >> 3)*NCOL + col)*8 + (k & 7);
    bHi[o] = (bf16_t)v;
}

// ===== MFMA GEMM v6: single bf16, B staged in LDS, deep A register prefetch =====
template<int K_REAL, int K_PAD, int NT, int GH, int PD, bool A_BF16, bool BIAS_EPI, bool ALPHA>
__global__ __launch_bounds__(256)
void mfma_gemm6_kernel(const void* __restrict__ A_, const bf16_t* __restrict__ bHi,
                       const float* __restrict__ bias, bf16_t* __restrict__ outH,
                       float* __restrict__ asrc_out, float* __restrict__ adst_out, int M)
{
    constexpr int NCOL   = NT * 16;
    constexpr int KSTEPS = K_PAD / 32;
    constexpr int KSPP   = GH / 4;            // k-steps per pass
    constexpr int NPASS  = KSTEPS / KSPP;
    constexpr int PELEM  = GH * NCOL * 8;     // bf16 elems per pass
    constexpr int SIT    = PELEM / 2048;      // stage iters (256 thr x 8 elems)
    static_assert(KSPP * NPASS == KSTEPS && SIT * 2048 == PELEM, "");
    __shared__ bf16_t blds[PELEM];

    int tid = threadIdx.x, lane = tid & 63, w = tid >> 6;
    int l15 = lane & 15, lg = lane >> 4;
    int m0 = (blockIdx.x*4 + w) * 16;
    int mrow = m0 + l15; if (mrow >= M) mrow = M - 1;   // clamp: stay for barriers

    const float*  arowF = (const float*) A_ + (size_t)mrow*K_REAL;
    const bf16_t* arowB = (const bf16_t*)A_ + (size_t)mrow*K_REAL;

    // ---- A prefetch prologue ----
    float4 pva[PD], pvb[PD];
    bf16x8 pab[PD];
    #pragma unroll
    for (int i = 0; i < PD; i++){
        int k0 = i*32 + lg*8;
        if (A_BF16){
            pab[i] = *(const bf16x8*)&arowB[k0];
        } else {
            pva[i] = (k0 + 3 < K_REAL) ? *(const float4*)&arowF[k0]     : (float4){0.f,0.f,0.f,0.f};
            pvb[i] = (k0 + 7 < K_REAL) ? *(const float4*)&arowF[k0 + 4] : (float4){0.f,0.f,0.f,0.f};
        }
    }

    f32x4 acc[NT];
    #pragma unroll
    for (int c = 0; c < NT; c++) acc[c] = (f32x4){0.f,0.f,0.f,0.f};

    #pragma unroll
    for (int p = 0; p < NPASS; p++){
        // ---- stage pass p's B chunk into LDS ----
        const bf16_t* gB = bHi + (size_t)p*PELEM;
        if (p) __syncthreads();
        #pragma unroll
        for (int it = 0; it < SIT; it++){
            int idx = (tid + it*256)*8;
            *(bf16x8*)&blds[idx] = *(const bf16x8*)&gB[idx];
        }
        __syncthreads();

        #pragma unroll
        for (int i = 0; i < KSPP; i++){
            const int ks = p*KSPP + i;
            const int sl = ks % PD;
            bf16x8 ah;
            if (A_BF16){
                ah = pab[sl];
            } else {
                float4 va = pva[sl], vb = pvb[sl];
                float f[8] = {va.x, va.y, va.z, va.w, vb.x, vb.y, vb.z, vb.w};
                #pragma unroll
                for (int q = 0; q < 8; q++) ah[q] = (bf16_t)f[q];
            }
            if (ks + PD < KSTEPS){            // refill
                int k0 = (ks + PD)*32 + lg*8;
                if (A_BF16){
                    pab[sl] = *(const bf16x8*)&arowB[k0];
                } else {
                    pva[sl] = (k0 + 3 < K_REAL) ? *(const float4*)&arowF[k0]     : (float4){0.f,0.f,0.f,0.f};
                    pvb[sl] = (k0 + 7 < K_REAL) ? *(const float4*)&arowF[k0 + 4] : (float4){0.f,0.f,0.f,0.f};
                }
            }
            int gloc = i*4 + lg;
            const bf16_t* b_base = &blds[(gloc*NCOL + l15)*8];
            #pragma unroll
            for (int c = 0; c < NT; c++){
                bf16x8 bh = *(const bf16x8*)&b_base[c*128];
                acc[c] = __builtin_amdgcn_mfma_f32_16x16x32_bf16(ah, bh, acc[c], 0,0,0);
            }
        }
    }

    // ---- epilogue: D col = lane&15, row = (lane>>4)*4 + reg; bf16 out ----
    #pragma unroll
    for (int c = 0; c < 8; c++){
        int col = c*16 + l15;
        float bv = BIAS_EPI ? bias[col] : 0.f;
        #pragma unroll
        for (int r = 0; r < 4; r++){
            int m = m0 + lg*4 + r;
            if (m < M) outH[(size_t)m*128 + col] = (bf16_t)(acc[c][r] + bv);
        }
    }
    if (ALPHA){
        #pragma unroll
        for (int r = 0; r < 4; r++){
            int m = m0 + lg*4 + r;
            if (m < M){
                float v = acc[8][r];
                if (l15 < 8) asrc_out[m*8 + l15]       = v;
                else         adst_out[m*8 + (l15 - 8)] = v;
            }
        }
    }
}

// ============== CSR build, XCD-partitioned by dst range ==============
__global__ __launch_bounds__(256)
void deg_part_kernel(const int* __restrict__ ei, int* __restrict__ deg){
    int part = blockIdx.x & 7;
    int bwp  = blockIdx.x >> 3;
    int nbp  = gridDim.x >> 3;
    int lo = part*PSZ, hi = lo + PSZ;
    for (int e = bwp*256 + threadIdx.x; e < E_TOT; e += nbp*256){
        int d = (e < N_EDGESI) ? ei[N_EDGESI + e] : (e - N_EDGESI);
        if (d >= lo && d < hi) atomicAdd(&deg[d], 1);
    }
}

__global__ __launch_bounds__(256)
void scatter_part_kernel(const int* __restrict__ ei, int* __restrict__ cursor,
                         int* __restrict__ col_src){
    int part = blockIdx.x & 7;
    int bwp  = blockIdx.x >> 3;
    int nbp  = gridDim.x >> 3;
    int lo = part*PSZ, hi = lo + PSZ;
    for (int e = bwp*256 + threadIdx.x; e < E_TOT; e += nbp*256){
        int d = (e < N_EDGESI) ? ei[N_EDGESI + e] : (e - N_EDGESI);
        if (d >= lo && d < hi){
            int s = (e < N_EDGESI) ? ei[e] : d;
            int pos = atomicAdd(&cursor[d], 1);
            col_src[pos] = s;
        }
    }
}

__global__ void scan_block_kernel(const int* __restrict__ deg, int* __restrict__ scanout,
                                  int* __restrict__ blocksums){
    __shared__ int buf[1024];
    int gid = blockIdx.x*1024 + threadIdx.x;
    int v = (gid < N_NODES) ? deg[gid] : 0;
    buf[threadIdx.x] = v;
    __syncthreads();
    for (int off = 1; off < 1024; off <<= 1){
        int t = (threadIdx.x >= off) ? buf[threadIdx.x - off] : 0;
        __syncthreads();
        buf[threadIdx.x] += t;
        __syncthreads();
    }
    if (gid < N_NODES) scanout[gid] = buf[threadIdx.x] - v;   // exclusive
    if (threadIdx.x == 1023) blocksums[blockIdx.x] = buf[1023];
}

__global__ void scan_sums_kernel(int* __restrict__ blocksums, int nb){
    int t = threadIdx.x;   // 64
    int orig = (t < nb) ? blocksums[t] : 0;
    int v = orig;
    #pragma unroll
    for (int off = 1; off < 64; off <<= 1){
        int u = __shfl_up(v, off);
        if (t >= off) v += u;
    }
    if (t < nb) blocksums[t] = v - orig;   // exclusive
}

__global__ void scan_add_kernel(const int* __restrict__ scanout, const int* __restrict__ blocksums,
                                int* __restrict__ row_ptr, int* __restrict__ cursor){
    int i = blockIdx.x*256 + threadIdx.x;
    if (i < N_NODES){
        int v = scanout[i] + blocksums[i >> 10];
        row_ptr[i] = v;
        cursor[i]  = v;
    }
    if (i == 0) row_ptr[N_NODES] = E_TOT;
}

// ===== fused per-dst softmax + aggregate + bias + ELU: one wave per node =====
// phase C: 8-wide gather groups, 2 independent acc pairs, no bounds checks.
// shfl the ROW BASE only (sreg*128); each lane adds its OWN channel offset.
__global__ __launch_bounds__(256)
void gat_aggregate_kernel(const int* __restrict__ row_ptr, const int* __restrict__ col_src,
                          const unsigned short* __restrict__ H, const float* __restrict__ a_s,
                          const float* __restrict__ a_d, const float* __restrict__ bias,
                          bf16_t* __restrict__ xout){
    __shared__ float alds[4][8][65];
    int wave = threadIdx.x >> 6;
    int lane = threadIdx.x & 63;
    int d = blockIdx.x*4 + wave;
    if (d >= N_NODES) return;
    int start = row_ptr[d], end = row_ptr[d + 1];
    int deg = end - start;                 // >= 1 (self loop)
    int hme = lane >> 3, seg = lane & 7;

    float ad_[8];
    {
        float4 t0 = *(const float4*)&a_d[d*8];
        float4 t1 = *(const float4*)&a_d[d*8 + 4];
        ad_[0]=t0.x; ad_[1]=t0.y; ad_[2]=t0.z; ad_[3]=t0.w;
        ad_[4]=t1.x; ad_[5]=t1.y; ad_[6]=t1.z; ad_[7]=t1.w;
    }

    float acc0 = 0.f, acc1 = 0.f, dh;
    unsigned hoff = 2u*lane;

    if (deg <= 64){
        bool act = lane < deg;
        int sreg = 0;
        float e[8];
        #pragma unroll
        for (int h = 0; h < 8; h++) e[h] = 0.f;
        if (act){
            sreg = col_src[start + lane];
            float4 s0 = *(const float4*)&a_s[sreg*8];
            float4 s1 = *(const float4*)&a_s[sreg*8 + 4];
            float as_[8] = {s0.x,s0.y,s0.z,s0.w,s1.x,s1.y,s1.z,s1.w};
            #pragma unroll
            for (int h = 0; h < 8; h++){
                float v = as_[h] + ad_[h];
                v = v > 0.f ? v : 0.2f*v;
                e[h] = __expf(fminf(v, 70.f));
            }
        }
        unsigned rbase = (unsigned)sreg * 128u;     // row base only — shfl this
        #pragma unroll
        for (int h = 0; h < 8; h++) alds[wave][h][lane] = e[h];

        const float* row = &alds[wave][hme][0];
        float s = 0.f;
        #pragma unroll
        for (int j = 0; j < 8; j++) s += row[seg*8 + j];
        s += __shfl_xor(s, 1); s += __shfl_xor(s, 2); s += __shfl_xor(s, 4);
        dh = 1.0f / s;

        // ---- phase C: groups of 8, two independent acc pairs ----
        float acc0b = 0.f, acc1b = 0.f;
        int iters = (deg + 7) >> 3;
        for (int it = 0; it < iters; it++){
            int p = it*8;
            unsigned o0 = __shfl(rbase, p+0) + hoff, o1 = __shfl(rbase, p+1) + hoff;
            unsigned o2 = __shfl(rbase, p+2) + hoff, o3 = __shfl(rbase, p+3) + hoff;
            unsigned o4 = __shfl(rbase, p+4) + hoff, o5 = __shfl(rbase, p+5) + hoff;
            unsigned o6 = __shfl(rbase, p+6) + hoff, o7 = __shfl(rbase, p+7) + hoff;
            unsigned g0 = *(const unsigned*)&H[o0];
            unsigned g1 = *(const unsigned*)&H[o1];
            unsigned g2 = *(const unsigned*)&H[o2];
            unsigned g3 = *(const unsigned*)&H[o3];
            unsigned g4 = *(const unsigned*)&H[o4];
            unsigned g5 = *(const unsigned*)&H[o5];
            unsigned g6 = *(const unsigned*)&H[o6];
            unsigned g7 = *(const unsigned*)&H[o7];
            float a0 = row[p+0], a1 = row[p+1], a2 = row[p+2], a3 = row[p+3];
            float a4 = row[p+4], a5 = row[p+5], a6 = row[p+6], a7 = row[p+7];
            acc0  += bflo(g0)*a0 + bflo(g2)*a2;
            acc1  += bfhi(g0)*a0 + bfhi(g2)*a2;
            acc0b += bflo(g1)*a1 + bflo(g3)*a3;
            acc1b += bfhi(g1)*a1 + bfhi(g3)*a3;
            acc0  += bflo(g4)*a4 + bflo(g6)*a6;
            acc1  += bfhi(g4)*a4 + bfhi(g6)*a6;
            acc0b += bflo(g5)*a5 + bflo(g7)*a7;
            acc1b += bfhi(g5)*a5 + bfhi(g7)*a7;
        }
        acc0 += acc0b;
        acc1 += acc1b;
    } else {
        float adh = ad_[hme];
        float s = 0.f;
        for (int p = start + seg; p < end; p += 8){
            int sn = col_src[p];
            float v = a_s[sn*8 + hme] + adh;
            v = v > 0.f ? v : 0.2f*v;
            s += __expf(fminf(v, 70.f));
        }
        s += __shfl_xor(s, 1); s += __shfl_xor(s, 2); s += __shfl_xor(s, 4);
        dh = 1.0f / s;
        for (int p = start; p < end; p++){
            int sn = col_src[p];
            float v = a_s[sn*8 + hme] + adh;
            v = v > 0.f ? v : 0.2f*v;
            float a = __expf(fminf(v, 70.f));
            unsigned g = *(const unsigned*)&H[(size_t)sn*128 + hoff];
            acc0 += bflo(g)*a;
            acc1 += bfhi(g)*a;
        }
    }

    float o0 = acc0*dh + bias[2*lane];
    float o1 = acc1*dh + bias[2*lane + 1];
    o0 = o0 > 0.f ? o0 : expm1f(o0);
    o1 = o1 > 0.f ? o1 : expm1f(o1);
    bf16x2 o = {(bf16_t)o0, (bf16_t)o1};
    *(bf16x2*)&xout[(size_t)d*HIDDEN + 2*lane] = o;
}

// ---- scores + loss fused ----
__global__ void head_kernel(const bf16_t* __restrict__ x, const int* __restrict__ tgt,
                            const float* __restrict__ w, const float* __restrict__ b,
                            float* __restrict__ dout){
    int t = threadIdx.x;   // 64 = BATCH
    const bf16_t* row = x + (size_t)tgt[t]*HIDDEN;
    float v = 0.f;
    #pragma unroll
    for (int c = 0; c < HIDDEN; c += 8){
        bf16x8 xv = *(const bf16x8*)&row[c];
        #pragma unroll
        for (int j = 0; j < 8; j++) v += (float)xv[j] * w[c + j];
    }
    float sc = v + b[0];
    dout[t] = sc;
    float neg = __shfl(sc, t + 32);
    float dlt = 1.0f - (sc - neg);
    float term = (t < 32) ? (dlt > 0.f ? dlt : 0.f) : 0.f;
    #pragma unroll
    for (int m = 32; m >= 1; m >>= 1) term += __shfl_xor(term, m);
    if (t == 0) dout[BATCH] = term * (1.0f/32.0f);
}

extern "C" void kernel_launch(void* const* d_in, const int* in_sizes, int n_in,
                              void* d_out, int out_size, void* d_ws, size_t ws_size,
                              hipStream_t stream) {
    const float* word   = (const float*)d_in[0];
    const int*   ei     = (const int*)  d_in[1];
    const int*   tgt    = (const int*)  d_in[2];
    const float* lin1W  = (const float*)d_in[4];
    const float* lin1b  = (const float*)d_in[5];
    const float* gatW   = (const float*)d_in[6];
    const float* attS   = (const float*)d_in[7];
    const float* attD   = (const float*)d_in[8];
    const float* gatB   = (const float*)d_in[9];
    const float* lin3W  = (const float*)d_in[10];
    const float* lin3b  = (const float*)d_in[11];

    char* ws = (char*)d_ws;
    size_t off = 0;
    bf16_t*  Xb      = (bf16_t*)(ws + off);  off += (size_t)N_NODES*HIDDEN*2;
    bf16_t*  Hb      = (bf16_t*)(ws + off);  off += (size_t)N_NODES*HIDDEN*2;
    float*   a_s     = (float*)(ws + off);   off += (size_t)N_NODES*HEADS*4;
    float*   a_d     = (float*)(ws + off);   off += (size_t)N_NODES*HEADS*4;
    int*     deg     = (int*)(ws + off);     off += (size_t)(N_NODES + 16)*4;
    int*     scantmp = (int*)(ws + off);     off += (size_t)(N_NODES + 16)*4;
    int*     bsums   = (int*)(ws + off);     off += 1024;
    int*     row_ptr = (int*)(ws + off);     off += (size_t)(N_NODES + 16)*4;
    int*     cursor  = (int*)(ws + off);     off += (size_t)(N_NODES + 16)*4;
    int*     col_src = (int*)(ws + off);     off += (size_t)E_TOT*4;
    bf16_t*  b1      = (bf16_t*)(ws + off);  off += (size_t)320*128*2;
    bf16_t*  b2      = (bf16_t*)(ws + off);  off += (size_t)128*144*2;

    const int NB = (N_NODES + 255)/256;
    const int SB = (N_NODES + 1023)/1024;
    const int GB = ((N_NODES + 15)/16 + 3)/4;   // 782 blocks, 64 rows each
    const int PB = 8*128;                        // partitioned CSR kernels

    // ---- CSR build (once), XCD-partitioned ----
    hipMemsetAsync(deg, 0, (size_t)N_NODES*4, stream);
    deg_part_kernel  <<<PB, 256, 0, stream>>>(ei, deg);
    scan_block_kernel<<<SB, 1024, 0, stream>>>(deg, scantmp, bsums);
    scan_sums_kernel <<<1, 64, 0, stream>>>(bsums, SB);
    scan_add_kernel  <<<NB, 256, 0, stream>>>(scantmp, bsums, row_ptr, cursor);
    scatter_part_kernel<<<PB, 256, 0, stream>>>(ei, cursor, col_src);

    // ---- lin1: Xb = bf16(word @ lin1_W + b) ----
    pack_b_kernel<INPUT, 320, 128, false><<<(320*128 + 255)/256, 256, 0, stream>>>(
        lin1W, nullptr, nullptr, b1);
    mfma_gemm6_kernel<INPUT, 320, 8, 8, 4, false, true, false><<<GB, 256, 0, stream>>>(
        word, b1, lin1b, Xb, nullptr, nullptr, N_NODES);

    for (int L = 0; L < 2; L++){
        const float* W = gatW + (size_t)L*HIDDEN*HIDDEN;
        pack_b_kernel<HIDDEN, 128, 144, true><<<(128*144 + 255)/256, 256, 0, stream>>>(
            W, attS + L*HEADS*HEAD_DIM, attD + L*HEADS*HEAD_DIM, b2);
        mfma_gemm6_kernel<HIDDEN, 128, 9, 16, 4, true, false, true><<<GB, 256, 0, stream>>>(
            Xb, b2, nullptr, Hb, a_s, a_d, N_NODES);
        gat_aggregate_kernel<<<(N_NODES + 3)/4, 256, 0, stream>>>(
            row_ptr, col_src, (const unsigned short*)Hb, a_s, a_d, gatB + L*HIDDEN, Xb);
    }

    head_kernel<<<1, 64, 0, stream>>>(Xb, tgt, lin3W, lin3b, (float*)d_out);
}

// Round 13
// 217.584 us; speedup vs baseline: 1.2752x; 1.0392x over previous
//
#include <hip/hip_runtime.h>
#include <math.h>

#define N_NODES 50000
#define N_EDGESI 800000
#define E_TOT   850000      // + self loops
#define HIDDEN  128
#define HEADS   8
#define HEAD_DIM 16
#define INPUT   300
#define BATCH   64
#define NPART   8
#define PSZ     6250        // N_NODES / NPART

typedef __bf16 bf16_t;
typedef bf16_t bf16x8 __attribute__((ext_vector_type(8)));
typedef bf16_t bf16x2 __attribute__((ext_vector_type(2)));
typedef float  f32x4  __attribute__((ext_vector_type(4)));
typedef float  f32x2  __attribute__((ext_vector_type(2)));

// ===== pack B (fp32 -> fragment-ready bf16 plane) + fused Wa =====
template<int K_REAL, int K_PAD, int NCOL, bool ALPHA>
__global__ void pack_b_kernel(const float* __restrict__ B128, const float* __restrict__ as,
                              const float* __restrict__ ad, bf16_t* __restrict__ bHi){
    int idx = blockIdx.x*256 + threadIdx.x;
    if (idx >= K_PAD*NCOL) return;
    int k = idx / NCOL, col = idx % NCOL;
    float v = 0.f;
    if (k < K_REAL){
        if (!ALPHA || col < 128){
            v = B128[k*128 + col];
        } else {
            int jj = col - 128;                       // 0..15
            const float* a = (jj < 8) ? (as + jj*16) : (ad + (jj-8)*16);
            const float* wrow = B128 + k*128 + (jj & 7)*16;
            float s = 0.f;
            #pragma unroll
            for (int d = 0; d < 16; d++) s += wrow[d]*a[d];
            v = s;
        }
    }
    int o = ((k >> 3)*NCOL + col)*8 + (k & 7);
    bHi[o] = (bf16_t)v;
}

// ===== MFMA GEMM v6: single bf16, B staged in LDS, deep A register prefetch =====
// OUT8: write fp8 e4m3 (HW packed cvt) instead of bf16.
template<int K_REAL, int K_PAD, int NT, int GH, int PD, bool A_BF16, bool BIAS_EPI, bool ALPHA, bool OUT8>
__global__ __launch_bounds__(256)
void mfma_gemm6_kernel(const void* __restrict__ A_, const bf16_t* __restrict__ bHi,
                       const float* __restrict__ bias, void* __restrict__ outP,
                       float* __restrict__ asrc_out, float* __restrict__ adst_out, int M)
{
    constexpr int NCOL   = NT * 16;
    constexpr int KSTEPS = K_PAD / 32;
    constexpr int KSPP   = GH / 4;            // k-steps per pass
    constexpr int NPASS  = KSTEPS / KSPP;
    constexpr int PELEM  = GH * NCOL * 8;     // bf16 elems per pass
    constexpr int SIT    = PELEM / 2048;      // stage iters (256 thr x 8 elems)
    static_assert(KSPP * NPASS == KSTEPS && SIT * 2048 == PELEM, "");
    __shared__ bf16_t blds[PELEM];

    int tid = threadIdx.x, lane = tid & 63, w = tid >> 6;
    int l15 = lane & 15, lg = lane >> 4;
    int m0 = (blockIdx.x*4 + w) * 16;
    int mrow = m0 + l15; if (mrow >= M) mrow = M - 1;   // clamp: stay for barriers

    const float*  arowF = (const float*) A_ + (size_t)mrow*K_REAL;
    const bf16_t* arowB = (const bf16_t*)A_ + (size_t)mrow*K_REAL;

    // ---- A prefetch prologue ----
    float4 pva[PD], pvb[PD];
    bf16x8 pab[PD];
    #pragma unroll
    for (int i = 0; i < PD; i++){
        int k0 = i*32 + lg*8;
        if (A_BF16){
            pab[i] = *(const bf16x8*)&arowB[k0];
        } else {
            pva[i] = (k0 + 3 < K_REAL) ? *(const float4*)&arowF[k0]     : (float4){0.f,0.f,0.f,0.f};
            pvb[i] = (k0 + 7 < K_REAL) ? *(const float4*)&arowF[k0 + 4] : (float4){0.f,0.f,0.f,0.f};
        }
    }

    f32x4 acc[NT];
    #pragma unroll
    for (int c = 0; c < NT; c++) acc[c] = (f32x4){0.f,0.f,0.f,0.f};

    #pragma unroll
    for (int p = 0; p < NPASS; p++){
        // ---- stage pass p's B chunk into LDS ----
        const bf16_t* gB = bHi + (size_t)p*PELEM;
        if (p) __syncthreads();
        #pragma unroll
        for (int it = 0; it < SIT; it++){
            int idx = (tid + it*256)*8;
            *(bf16x8*)&blds[idx] = *(const bf16x8*)&gB[idx];
        }
        __syncthreads();

        #pragma unroll
        for (int i = 0; i < KSPP; i++){
            const int ks = p*KSPP + i;
            const int sl = ks % PD;
            bf16x8 ah;
            if (A_BF16){
                ah = pab[sl];
            } else {
                float4 va = pva[sl], vb = pvb[sl];
                float f[8] = {va.x, va.y, va.z, va.w, vb.x, vb.y, vb.z, vb.w};
                #pragma unroll
                for (int q = 0; q < 8; q++) ah[q] = (bf16_t)f[q];
            }
            if (ks + PD < KSTEPS){            // refill
                int k0 = (ks + PD)*32 + lg*8;
                if (A_BF16){
                    pab[sl] = *(const bf16x8*)&arowB[k0];
                } else {
                    pva[sl] = (k0 + 3 < K_REAL) ? *(const float4*)&arowF[k0]     : (float4){0.f,0.f,0.f,0.f};
                    pvb[sl] = (k0 + 7 < K_REAL) ? *(const float4*)&arowF[k0 + 4] : (float4){0.f,0.f,0.f,0.f};
                }
            }
            int gloc = i*4 + lg;
            const bf16_t* b_base = &blds[(gloc*NCOL + l15)*8];
            #pragma unroll
            for (int c = 0; c < NT; c++){
                bf16x8 bh = *(const bf16x8*)&b_base[c*128];
                acc[c] = __builtin_amdgcn_mfma_f32_16x16x32_bf16(ah, bh, acc[c], 0,0,0);
            }
        }
    }

    // ---- epilogue: D col = lane&15, row = (lane>>4)*4 + reg ----
    #pragma unroll
    for (int c = 0; c < 8; c++){
        int col = c*16 + l15;
        float bv = BIAS_EPI ? bias[col] : 0.f;
        #pragma unroll
        for (int r = 0; r < 4; r++){
            int m = m0 + lg*4 + r;
            if (m < M){
                float v = acc[c][r] + bv;
                if (OUT8){
                    int pk = __builtin_amdgcn_cvt_pk_fp8_f32(v, v, 0, false);
                    ((unsigned char*)outP)[(size_t)m*128 + col] = (unsigned char)(pk & 0xff);
                } else {
                    ((bf16_t*)outP)[(size_t)m*128 + col] = (bf16_t)v;
                }
            }
        }
    }
    if (ALPHA){
        #pragma unroll
        for (int r = 0; r < 4; r++){
            int m = m0 + lg*4 + r;
            if (m < M){
                float v = acc[8][r];
                if (l15 < 8) asrc_out[m*8 + l15]       = v;
                else         adst_out[m*8 + (l15 - 8)] = v;
            }
        }
    }
}

// ============== CSR build, XCD-partitioned by dst range ==============
__global__ __launch_bounds__(256)
void deg_part_kernel(const int* __restrict__ ei, int* __restrict__ deg){
    int part = blockIdx.x & 7;
    int bwp  = blockIdx.x >> 3;
    int nbp  = gridDim.x >> 3;
    int lo = part*PSZ, hi = lo + PSZ;
    for (int e = bwp*256 + threadIdx.x; e < E_TOT; e += nbp*256){
        int d = (e < N_EDGESI) ? ei[N_EDGESI + e] : (e - N_EDGESI);
        if (d >= lo && d < hi) atomicAdd(&deg[d], 1);
    }
}

__global__ __launch_bounds__(256)
void scatter_part_kernel(const int* __restrict__ ei, int* __restrict__ cursor,
                         int* __restrict__ col_src){
    int part = blockIdx.x & 7;
    int bwp  = blockIdx.x >> 3;
    int nbp  = gridDim.x >> 3;
    int lo = part*PSZ, hi = lo + PSZ;
    for (int e = bwp*256 + threadIdx.x; e < E_TOT; e += nbp*256){
        int d = (e < N_EDGESI) ? ei[N_EDGESI + e] : (e - N_EDGESI);
        if (d >= lo && d < hi){
            int s = (e < N_EDGESI) ? ei[e] : d;
            int pos = atomicAdd(&cursor[d], 1);
            col_src[pos] = s;
        }
    }
}

__global__ void scan_block_kernel(const int* __restrict__ deg, int* __restrict__ scanout,
                                  int* __restrict__ blocksums){
    __shared__ int buf[1024];
    int gid = blockIdx.x*1024 + threadIdx.x;
    int v = (gid < N_NODES) ? deg[gid] : 0;
    buf[threadIdx.x] = v;
    __syncthreads();
    for (int off = 1; off < 1024; off <<= 1){
        int t = (threadIdx.x >= off) ? buf[threadIdx.x - off] : 0;
        __syncthreads();
        buf[threadIdx.x] += t;
        __syncthreads();
    }
    if (gid < N_NODES) scanout[gid] = buf[threadIdx.x] - v;   // exclusive
    if (threadIdx.x == 1023) blocksums[blockIdx.x] = buf[1023];
}

__global__ void scan_sums_kernel(int* __restrict__ blocksums, int nb){
    int t = threadIdx.x;   // 64
    int orig = (t < nb) ? blocksums[t] : 0;
    int v = orig;
    #pragma unroll
    for (int off = 1; off < 64; off <<= 1){
        int u = __shfl_up(v, off);
        if (t >= off) v += u;
    }
    if (t < nb) blocksums[t] = v - orig;   // exclusive
}

__global__ void scan_add_kernel(const int* __restrict__ scanout, const int* __restrict__ blocksums,
                                int* __restrict__ row_ptr, int* __restrict__ cursor){
    int i = blockIdx.x*256 + threadIdx.x;
    if (i < N_NODES){
        int v = scanout[i] + blocksums[i >> 10];
        row_ptr[i] = v;
        cursor[i]  = v;
    }
    if (i == 0) row_ptr[N_NODES] = E_TOT;
}

// ===== fused per-dst softmax + aggregate + bias + ELU: one wave per node =====
// H is fp8 e4m3 (1 byte/channel); decode with HW packed cvt.
__global__ __launch_bounds__(256)
void gat_aggregate_kernel(const int* __restrict__ row_ptr, const int* __restrict__ col_src,
                          const unsigned char* __restrict__ H8, const float* __restrict__ a_s,
                          const float* __restrict__ a_d, const float* __restrict__ bias,
                          bf16_t* __restrict__ xout){
    __shared__ float alds[4][8][65];
    int wave = threadIdx.x >> 6;
    int lane = threadIdx.x & 63;
    int d = blockIdx.x*4 + wave;
    if (d >= N_NODES) return;
    int start = row_ptr[d], end = row_ptr[d + 1];
    int deg = end - start;                 // >= 1 (self loop)
    int hme = lane >> 3, seg = lane & 7;

    float ad_[8];
    {
        float4 t0 = *(const float4*)&a_d[d*8];
        float4 t1 = *(const float4*)&a_d[d*8 + 4];
        ad_[0]=t0.x; ad_[1]=t0.y; ad_[2]=t0.z; ad_[3]=t0.w;
        ad_[4]=t1.x; ad_[5]=t1.y; ad_[6]=t1.z; ad_[7]=t1.w;
    }

    float acc0 = 0.f, acc1 = 0.f, dh;
    unsigned hoff = 2u*lane;               // byte offset of this lane's 2 channels

    if (deg <= 64){
        bool act = lane < deg;
        int sreg = 0;
        float e[8];
        #pragma unroll
        for (int h = 0; h < 8; h++) e[h] = 0.f;
        if (act){
            sreg = col_src[start + lane];
            float4 s0 = *(const float4*)&a_s[sreg*8];
            float4 s1 = *(const float4*)&a_s[sreg*8 + 4];
            float as_[8] = {s0.x,s0.y,s0.z,s0.w,s1.x,s1.y,s1.z,s1.w};
            #pragma unroll
            for (int h = 0; h < 8; h++){
                float v = as_[h] + ad_[h];
                v = v > 0.f ? v : 0.2f*v;
                e[h] = __expf(fminf(v, 70.f));
            }
        }
        unsigned rbase = (unsigned)sreg * 128u;     // byte row base — shfl this
        #pragma unroll
        for (int h = 0; h < 8; h++) alds[wave][h][lane] = e[h];

        const float* row = &alds[wave][hme][0];
        float s = 0.f;
        #pragma unroll
        for (int j = 0; j < 8; j++) s += row[seg*8 + j];
        s += __shfl_xor(s, 1); s += __shfl_xor(s, 2); s += __shfl_xor(s, 4);
        dh = 1.0f / s;

        // ---- phase C: groups of 8, two independent acc pairs ----
        float acc0b = 0.f, acc1b = 0.f;
        int iters = (deg + 7) >> 3;
        for (int it = 0; it < iters; it++){
            int p = it*8;
            unsigned o0 = __shfl(rbase, p+0) + hoff, o1 = __shfl(rbase, p+1) + hoff;
            unsigned o2 = __shfl(rbase, p+2) + hoff, o3 = __shfl(rbase, p+3) + hoff;
            unsigned o4 = __shfl(rbase, p+4) + hoff, o5 = __shfl(rbase, p+5) + hoff;
            unsigned o6 = __shfl(rbase, p+6) + hoff, o7 = __shfl(rbase, p+7) + hoff;
            unsigned short g0 = *(const unsigned short*)&H8[o0];
            unsigned short g1 = *(const unsigned short*)&H8[o1];
            unsigned short g2 = *(const unsigned short*)&H8[o2];
            unsigned short g3 = *(const unsigned short*)&H8[o3];
            unsigned short g4 = *(const unsigned short*)&H8[o4];
            unsigned short g5 = *(const unsigned short*)&H8[o5];
            unsigned short g6 = *(const unsigned short*)&H8[o6];
            unsigned short g7 = *(const unsigned short*)&H8[o7];
            float a0 = row[p+0], a1 = row[p+1], a2 = row[p+2], a3 = row[p+3];
            float a4 = row[p+4], a5 = row[p+5], a6 = row[p+6], a7 = row[p+7];
            f32x2 f0 = __builtin_amdgcn_cvt_pk_f32_fp8((int)g0, false);
            f32x2 f1 = __builtin_amdgcn_cvt_pk_f32_fp8((int)g1, false);
            f32x2 f2 = __builtin_amdgcn_cvt_pk_f32_fp8((int)g2, false);
            f32x2 f3 = __builtin_amdgcn_cvt_pk_f32_fp8((int)g3, false);
            f32x2 f4 = __builtin_amdgcn_cvt_pk_f32_fp8((int)g4, false);
            f32x2 f5 = __builtin_amdgcn_cvt_pk_f32_fp8((int)g5, false);
            f32x2 f6 = __builtin_amdgcn_cvt_pk_f32_fp8((int)g6, false);
            f32x2 f7 = __builtin_amdgcn_cvt_pk_f32_fp8((int)g7, false);
            acc0  += f0.x*a0 + f2.x*a2;
            acc1  += f0.y*a0 + f2.y*a2;
            acc0b += f1.x*a1 + f3.x*a3;
            acc1b += f1.y*a1 + f3.y*a3;
            acc0  += f4.x*a4 + f6.x*a6;
            acc1  += f4.y*a4 + f6.y*a6;
            acc0b += f5.x*a5 + f7.x*a7;
            acc1b += f5.y*a5 + f7.y*a7;
        }
        acc0 += acc0b;
        acc1 += acc1b;
    } else {
        float adh = ad_[hme];
        float s = 0.f;
        for (int p = start + seg; p < end; p += 8){
            int sn = col_src[p];
            float v = a_s[sn*8 + hme] + adh;
            v = v > 0.f ? v : 0.2f*v;
            s += __expf(fminf(v, 70.f));
        }
        s += __shfl_xor(s, 1); s += __shfl_xor(s, 2); s += __shfl_xor(s, 4);
        dh = 1.0f / s;
        for (int p = start; p < end; p++){
            int sn = col_src[p];
            float v = a_s[sn*8 + hme] + adh;
            v = v > 0.f ? v : 0.2f*v;
            float a = __expf(fminf(v, 70.f));
            unsigned short g = *(const unsigned short*)&H8[(size_t)sn*128 + hoff];
            f32x2 f = __builtin_amdgcn_cvt_pk_f32_fp8((int)g, false);
            acc0 += f.x*a;
            acc1 += f.y*a;
        }
    }

    float o0 = acc0*dh + bias[2*lane];
    float o1 = acc1*dh + bias[2*lane + 1];
    o0 = o0 > 0.f ? o0 : expm1f(o0);
    o1 = o1 > 0.f ? o1 : expm1f(o1);
    bf16x2 o = {(bf16_t)o0, (bf16_t)o1};
    *(bf16x2*)&xout[(size_t)d*HIDDEN + 2*lane] = o;
}

// ---- scores + loss fused ----
__global__ void head_kernel(const bf16_t* __restrict__ x, const int* __restrict__ tgt,
                            const float* __restrict__ w, const float* __restrict__ b,
                            float* __restrict__ dout){
    int t = threadIdx.x;   // 64 = BATCH
    const bf16_t* row = x + (size_t)tgt[t]*HIDDEN;
    float v = 0.f;
    #pragma unroll
    for (int c = 0; c < HIDDEN; c += 8){
        bf16x8 xv = *(const bf16x8*)&row[c];
        #pragma unroll
        for (int j = 0; j < 8; j++) v += (float)xv[j] * w[c + j];
    }
    float sc = v + b[0];
    dout[t] = sc;
    float neg = __shfl(sc, t + 32);
    float dlt = 1.0f - (sc - neg);
    float term = (t < 32) ? (dlt > 0.f ? dlt : 0.f) : 0.f;
    #pragma unroll
    for (int m = 32; m >= 1; m >>= 1) term += __shfl_xor(term, m);
    if (t == 0) dout[BATCH] = term * (1.0f/32.0f);
}

extern "C" void kernel_launch(void* const* d_in, const int* in_sizes, int n_in,
                              void* d_out, int out_size, void* d_ws, size_t ws_size,
                              hipStream_t stream) {
    const float* word   = (const float*)d_in[0];
    const int*   ei     = (const int*)  d_in[1];
    const int*   tgt    = (const int*)  d_in[2];
    const float* lin1W  = (const float*)d_in[4];
    const float* lin1b  = (const float*)d_in[5];
    const float* gatW   = (const float*)d_in[6];
    const float* attS   = (const float*)d_in[7];
    const float* attD   = (const float*)d_in[8];
    const float* gatB   = (const float*)d_in[9];
    const float* lin3W  = (const float*)d_in[10];
    const float* lin3b  = (const float*)d_in[11];

    char* ws = (char*)d_ws;
    size_t off = 0;
    bf16_t*        Xb      = (bf16_t*)(ws + off);        off += (size_t)N_NODES*HIDDEN*2;
    unsigned char* H8      = (unsigned char*)(ws + off); off += (size_t)N_NODES*HIDDEN;
    off = (off + 15) & ~(size_t)15;
    float*   a_s     = (float*)(ws + off);   off += (size_t)N_NODES*HEADS*4;
    float*   a_d     = (float*)(ws + off);   off += (size_t)N_NODES*HEADS*4;
    int*     deg     = (int*)(ws + off);     off += (size_t)(N_NODES + 16)*4;
    int*     scantmp = (int*)(ws + off);     off += (size_t)(N_NODES + 16)*4;
    int*     bsums   = (int*)(ws + off);     off += 1024;
    int*     row_ptr = (int*)(ws + off);     off += (size_t)(N_NODES + 16)*4;
    int*     cursor  = (int*)(ws + off);     off += (size_t)(N_NODES + 16)*4;
    int*     col_src = (int*)(ws + off);     off += (size_t)E_TOT*4;
    bf16_t*  b1      = (bf16_t*)(ws + off);  off += (size_t)320*128*2;
    bf16_t*  b2      = (bf16_t*)(ws + off);  off += (size_t)128*144*2;

    const int NB = (N_NODES + 255)/256;
    const int SB = (N_NODES + 1023)/1024;
    const int GB = ((N_NODES + 15)/16 + 3)/4;   // 782 blocks, 64 rows each
    const int PB = 8*128;                        // partitioned CSR kernels

    // ---- CSR build (once), XCD-partitioned ----
    hipMemsetAsync(deg, 0, (size_t)N_NODES*4, stream);
    deg_part_kernel  <<<PB, 256, 0, stream>>>(ei, deg);
    scan_block_kernel<<<SB, 1024, 0, stream>>>(deg, scantmp, bsums);
    scan_sums_kernel <<<1, 64, 0, stream>>>(bsums, SB);
    scan_add_kernel  <<<NB, 256, 0, stream>>>(scantmp, bsums, row_ptr, cursor);
    scatter_part_kernel<<<PB, 256, 0, stream>>>(ei, cursor, col_src);

    // ---- lin1: Xb = bf16(word @ lin1_W + b) ----
    pack_b_kernel<INPUT, 320, 128, false><<<(320*128 + 255)/256, 256, 0, stream>>>(
        lin1W, nullptr, nullptr, b1);
    mfma_gemm6_kernel<INPUT, 320, 8, 8, 4, false, true, false, false><<<GB, 256, 0, stream>>>(
        word, b1, lin1b, Xb, nullptr, nullptr, N_NODES);

    for (int L = 0; L < 2; L++){
        const float* W = gatW + (size_t)L*HIDDEN*HIDDEN;
        pack_b_kernel<HIDDEN, 128, 144, true><<<(128*144 + 255)/256, 256, 0, stream>>>(
            W, attS + L*HEADS*HEAD_DIM, attD + L*HEADS*HEAD_DIM, b2);
        mfma_gemm6_kernel<HIDDEN, 128, 9, 16, 4, true, false, true, true><<<GB, 256, 0, stream>>>(
            Xb, b2, nullptr, H8, a_s, a_d, N_NODES);
        gat_aggregate_kernel<<<(N_NODES + 3)/4, 256, 0, stream>>>(
            row_ptr, col_src, H8, a_s, a_d, gatB + L*HIDDEN, Xb);
    }

    head_kernel<<<1, 64, 0, stream>>>(Xb, tgt, lin3W, lin3b, (float*)d_out);
}